// Round 1
// baseline (3186.805 us; speedup 1.0000x reference)
//
#include <hip/hip_runtime.h>
#include <math.h>

#define FDIM 256
#define NBF 20
#define PI_F 3.14159265358979323846f

__device__ __forceinline__ float silu_f(float x) {
    return x / (1.0f + __expf(-x));
}

// ---------------------------------------------------------------------------
// Tiled fp32 GEMM: C = act(A(MxK) @ B(KxN) + bias(N)) ; ACT=1 -> SiLU
// BM=BN=64, BK=16, 256 threads, 4x4 per thread.
// ---------------------------------------------------------------------------
template<int ACT>
__global__ __launch_bounds__(256)
void gemm_kernel(const float* __restrict__ A, const float* __restrict__ B,
                 const float* __restrict__ bias, float* __restrict__ C,
                 int M, int N, int K)
{
    __shared__ float As[16][68];   // [k][m], padded
    __shared__ float Bs[16][64];   // [k][n]

    const int bm = blockIdx.y * 64;
    const int bn = blockIdx.x * 64;
    const int tid = threadIdx.x;
    const int tr = tid >> 4;        // 0..15 (row group)
    const int tc = tid & 15;        // 0..15 (col group)
    const int lar = tid >> 2;       // 0..63 A-tile row
    const int lac = (tid & 3) << 2; // 0,4,8,12 A-tile col (float4)
    const int lbr = tid >> 4;       // 0..15 B-tile row
    const int lbc = (tid & 15) << 2;// 0..60 B-tile col (float4)

    float acc[4][4] = {};
    const int arow = min(bm + lar, M - 1);

    for (int k0 = 0; k0 < K; k0 += 16) {
        const float4 av = *(const float4*)&A[(size_t)arow * K + k0 + lac];
        const float4 bv = *(const float4*)&B[(size_t)(k0 + lbr) * N + bn + lbc];
        __syncthreads();
        As[lac + 0][lar] = av.x;
        As[lac + 1][lar] = av.y;
        As[lac + 2][lar] = av.z;
        As[lac + 3][lar] = av.w;
        *(float4*)&Bs[lbr][lbc] = bv;
        __syncthreads();
#pragma unroll
        for (int k = 0; k < 16; ++k) {
            float a[4], b[4];
            *(float4*)a = *(const float4*)&As[k][tr << 2];
            *(float4*)b = *(const float4*)&Bs[k][tc << 2];
#pragma unroll
            for (int i = 0; i < 4; ++i)
#pragma unroll
                for (int j = 0; j < 4; ++j)
                    acc[i][j] = fmaf(a[i], b[j], acc[i][j]);
        }
    }

#pragma unroll
    for (int i = 0; i < 4; ++i) {
        const int row = bm + (tr << 2) + i;
        if (row < M) {
#pragma unroll
            for (int j = 0; j < 4; ++j) {
                const int col = bn + (tc << 2) + j;
                float v = acc[i][j] + bias[col];
                if (ACT) v = silu_f(v);
                C[(size_t)row * N + col] = v;
            }
        }
    }
}

// ---------------------------------------------------------------------------
// ns[a][f] = embed[Z[a]][f]
// ---------------------------------------------------------------------------
__global__ void init_ns_kernel(const int* __restrict__ Z,
                               const float* __restrict__ embed,
                               float* __restrict__ ns, int n_atoms)
{
    int i = blockIdx.x * 256 + threadIdx.x;
    if (i >= n_atoms * FDIM) return;
    int a = i >> 8, f = i & 255;
    ns[i] = embed[Z[a] * FDIM + f];
}

// ---------------------------------------------------------------------------
// Edge message pass. One block (256 thr) handles `epb` edges.
// Thread f holds filter-weight columns f, f+256, f+512 in registers.
// ---------------------------------------------------------------------------
__global__ __launch_bounds__(256)
void edge_kernel(const int* __restrict__ edge,
                 const float* __restrict__ edge_diff,
                 const float* __restrict__ edge_dist,
                 const float* __restrict__ wf,    // (20,768) this layer
                 const float* __restrict__ bf,    // (768)
                 const float* __restrict__ so,    // (n_atoms,768) scalar_out
                 const float* __restrict__ nv_old,// (n_atoms,3,256)
                 float* __restrict__ ns,          // (n_atoms,256) += msg_s
                 float* __restrict__ nv_new,      // (n_atoms,3,256) += msg_v
                 int n_edges, int epb)
{
    const int f = threadIdx.x;
    float w0[NBF], w1[NBF], w2[NBF];
#pragma unroll
    for (int k = 0; k < NBF; ++k) {
        w0[k] = wf[k * 768 + f];
        w1[k] = wf[k * 768 + 256 + f];
        w2[k] = wf[k * 768 + 512 + f];
    }
    const float b0 = bf[f], b1 = bf[256 + f], b2 = bf[512 + f];

    const int e0 = blockIdx.x * epb;
    const int e1 = min(e0 + epb, n_edges);
    for (int e = e0; e < e1; ++e) {
        const int recv = edge[2 * e + 0];
        const int send = edge[2 * e + 1];
        const float dist = edge_dist[e];
        const float inv = 1.0f / dist;
        const float ux = edge_diff[3 * e + 0] * inv;
        const float uy = edge_diff[3 * e + 1] * inv;
        const float uz = edge_diff[3 * e + 2] * inv;
        const float fcut = (dist < 5.0f)
            ? 0.5f * (__cosf(dist * (PI_F / 5.0f)) + 1.0f) : 0.0f;

        float f0 = b0, f1 = b1, f2 = b2;
#pragma unroll
        for (int k = 0; k < NBF; ++k) {
            const float r = __sinf(dist * ((k + 1) * (PI_F / 5.0f))) * inv;
            f0 = fmaf(r, w0[k], f0);
            f1 = fmaf(r, w1[k], f1);
            f2 = fmaf(r, w2[k], f2);
        }
        f0 *= fcut; f1 *= fcut; f2 *= fcut;

        const float* sp = so + (size_t)send * 768;
        const float gv = f0 * sp[f];
        const float ge = f1 * sp[256 + f];
        const float ms = f2 * sp[512 + f];

        atomicAdd(&ns[(size_t)recv * 256 + f], ms);

        const float* nvp = nv_old + (size_t)send * 768;
        float* nvd = nv_new + (size_t)recv * 768;
        atomicAdd(&nvd[f],       fmaf(nvp[f],       gv, ux * ge));
        atomicAdd(&nvd[256 + f], fmaf(nvp[256 + f], gv, uy * ge));
        atomicAdd(&nvd[512 + f], fmaf(nvp[512 + f], gv, uz * ge));
    }
}

// ---------------------------------------------------------------------------
// cat[a][0:256] = |Vv[a,:,f]| ; cat[a][256:512] = ns[a][f]
// ---------------------------------------------------------------------------
__global__ void vncat_kernel(const float* __restrict__ Vv,
                             const float* __restrict__ ns,
                             float* __restrict__ cat, int n_atoms)
{
    int i = blockIdx.x * 256 + threadIdx.x;
    if (i >= n_atoms * FDIM) return;
    int a = i >> 8, f = i & 255;
    const float v0 = Vv[(size_t)a * 768 + f];
    const float v1 = Vv[(size_t)a * 768 + 256 + f];
    const float v2 = Vv[(size_t)a * 768 + 512 + f];
    cat[(size_t)a * 512 + f] = sqrtf(v0 * v0 + v1 * v1 + v2 * v2);
    cat[(size_t)a * 512 + 256 + f] = ns[i];
}

// ---------------------------------------------------------------------------
// nv += a_vv * Uv ; ns += a_sv * sum_d(Uv*Vv) + a_ss
// ---------------------------------------------------------------------------
__global__ void apply_update_kernel(const float* __restrict__ mlp,
                                    const float* __restrict__ Uv,
                                    const float* __restrict__ Vv,
                                    float* __restrict__ nv,
                                    float* __restrict__ ns, int n_atoms)
{
    int i = blockIdx.x * 256 + threadIdx.x;
    if (i >= n_atoms * FDIM) return;
    int a = i >> 8, f = i & 255;
    const float avv = mlp[(size_t)a * 768 + f];
    const float asv = mlp[(size_t)a * 768 + 256 + f];
    const float ass = mlp[(size_t)a * 768 + 512 + f];
    float dot = 0.0f;
#pragma unroll
    for (int d = 0; d < 3; ++d) {
        const size_t idx = (size_t)a * 768 + d * 256 + f;
        const float u = Uv[idx];
        const float v = Vv[idx];
        nv[idx] = fmaf(avv, u, nv[idx]);
        dot = fmaf(u, v, dot);
    }
    ns[i] = ns[i] + fmaf(asv, dot, ass);
}

// ---------------------------------------------------------------------------
// energy[a] = dot(hid[a], ro_w2) + ro_b2   (hid already silu'd)
// ---------------------------------------------------------------------------
__global__ void readout_kernel(const float* __restrict__ hid,
                               const float* __restrict__ w2,
                               const float* __restrict__ b2,
                               float* __restrict__ out, int n_atoms)
{
    const int a = blockIdx.x;
    const int lane = threadIdx.x; // 64
    const float* h = hid + (size_t)a * FDIM;
    float s = 0.0f;
#pragma unroll
    for (int i = 0; i < 4; ++i)
        s += h[lane + 64 * i] * w2[lane + 64 * i];
#pragma unroll
    for (int off = 32; off > 0; off >>= 1)
        s += __shfl_down(s, off);
    if (lane == 0) out[a] = s + b2[0];
}

// ---------------------------------------------------------------------------

static inline void launch_gemm(int act, const float* A, const float* B,
                               const float* bias, float* C,
                               int M, int N, int K, hipStream_t s)
{
    dim3 grid(N / 64, (M + 63) / 64);
    if (act)
        gemm_kernel<1><<<grid, 256, 0, s>>>(A, B, bias, C, M, N, K);
    else
        gemm_kernel<0><<<grid, 256, 0, s>>>(A, B, bias, C, M, N, K);
}

extern "C" void kernel_launch(void* const* d_in, const int* in_sizes, int n_in,
                              void* d_out, int out_size, void* d_ws, size_t ws_size,
                              hipStream_t stream)
{
    const int*   Z            = (const int*)  d_in[0];
    const int*   edge         = (const int*)  d_in[1];
    const float* edge_diff    = (const float*)d_in[2];
    const float* edge_dist    = (const float*)d_in[3];
    const float* embed        = (const float*)d_in[4];
    const float* msg_w_filter = (const float*)d_in[5];
    const float* msg_b_filter = (const float*)d_in[6];
    const float* msg_w1       = (const float*)d_in[7];
    const float* msg_b1       = (const float*)d_in[8];
    const float* msg_w2       = (const float*)d_in[9];
    const float* msg_b2       = (const float*)d_in[10];
    const float* upd_wU       = (const float*)d_in[11];
    const float* upd_bU       = (const float*)d_in[12];
    const float* upd_wV       = (const float*)d_in[13];
    const float* upd_bV       = (const float*)d_in[14];
    const float* upd_w1       = (const float*)d_in[15];
    const float* upd_b1       = (const float*)d_in[16];
    const float* upd_w2       = (const float*)d_in[17];
    const float* upd_b2       = (const float*)d_in[18];
    const float* ro_w1        = (const float*)d_in[19];
    const float* ro_b1        = (const float*)d_in[20];
    const float* ro_w2        = (const float*)d_in[21];
    const float* ro_b2        = (const float*)d_in[22];
    float* out = (float*)d_out;

    const int n_atoms = in_sizes[0];
    const int n_edges = in_sizes[1] / 2;

    float* p   = (float*)d_ws;
    float* ns  = p; p += (size_t)n_atoms * 256;
    float* nvA = p; p += (size_t)n_atoms * 768;
    float* nvB = p; p += (size_t)n_atoms * 768;
    float* so  = p; p += (size_t)n_atoms * 768;
    float* hid = p; p += (size_t)n_atoms * 256;
    float* Uv  = p; p += (size_t)n_atoms * 768;
    float* Vv  = p; p += (size_t)n_atoms * 768;
    float* cat = p; p += (size_t)n_atoms * 512;

    hipMemsetAsync(nvA, 0, (size_t)n_atoms * 768 * sizeof(float), stream);
    init_ns_kernel<<<(n_atoms * 256 + 255) / 256, 256, 0, stream>>>(Z, embed, ns, n_atoms);

    float* nv_old = nvA;
    float* nv_new = nvB;

    const int epb = (n_edges + 2047) / 2048;
    const int eblocks = (n_edges + epb - 1) / epb;

    for (int l = 0; l < 3; ++l) {
        // scalar_out = silu(ns @ msg_w1 + b1) @ msg_w2 + b2
        launch_gemm(1, ns, msg_w1 + (size_t)l * 256 * 256, msg_b1 + l * 256,
                    hid, n_atoms, 256, 256, stream);
        launch_gemm(0, hid, msg_w2 + (size_t)l * 256 * 768, msg_b2 + l * 768,
                    so, n_atoms, 768, 256, stream);

        // nv_new starts as copy of nv_old (segment_sum is +=)
        hipMemcpyAsync(nv_new, nv_old, (size_t)n_atoms * 768 * sizeof(float),
                       hipMemcpyDeviceToDevice, stream);

        edge_kernel<<<eblocks, 256, 0, stream>>>(
            edge, edge_diff, edge_dist,
            msg_w_filter + (size_t)l * NBF * 768, msg_b_filter + l * 768,
            so, nv_old, ns, nv_new, n_edges, epb);

        // Uv / Vv  (treat nv as (3*n_atoms, 256))
        launch_gemm(0, nv_new, upd_wU + (size_t)l * 256 * 256, upd_bU + l * 256,
                    Uv, n_atoms * 3, 256, 256, stream);
        launch_gemm(0, nv_new, upd_wV + (size_t)l * 256 * 256, upd_bV + l * 256,
                    Vv, n_atoms * 3, 256, 256, stream);

        vncat_kernel<<<(n_atoms * 256 + 255) / 256, 256, 0, stream>>>(Vv, ns, cat, n_atoms);

        launch_gemm(1, cat, upd_w1 + (size_t)l * 512 * 256, upd_b1 + l * 256,
                    hid, n_atoms, 256, 512, stream);
        launch_gemm(0, hid, upd_w2 + (size_t)l * 256 * 768, upd_b2 + l * 768,
                    so, n_atoms, 768, 256, stream);

        apply_update_kernel<<<(n_atoms * 256 + 255) / 256, 256, 0, stream>>>(
            so, Uv, Vv, nv_new, ns, n_atoms);

        float* t = nv_old; nv_old = nv_new; nv_new = t;
    }

    // readout
    launch_gemm(1, nv_old == nvA ? ns : ns, ro_w1, ro_b1, hid, n_atoms, 256, 256, stream);
    readout_kernel<<<n_atoms, 64, 0, stream>>>(hid, ro_w2, ro_b2, out, n_atoms);
}

// Round 3
// 1782.164 us; speedup vs baseline: 1.7882x; 1.7882x over previous
//
#include <hip/hip_runtime.h>
#include <math.h>

#define FDIM 256
#define NBF 20
#define PI_F 3.14159265358979323846f

__device__ __forceinline__ float silu_f(float x) {
    return x / (1.0f + __expf(-x));
}

// ---------------------------------------------------------------------------
// Tiled fp32 GEMM: C = act(A(MxK) @ B(KxN) + bias(N)) ; ACT=1 -> SiLU
// ---------------------------------------------------------------------------
template<int ACT>
__global__ __launch_bounds__(256)
void gemm_kernel(const float* __restrict__ A, const float* __restrict__ B,
                 const float* __restrict__ bias, float* __restrict__ C,
                 int M, int N, int K)
{
    __shared__ float As[16][68];
    __shared__ float Bs[16][64];

    const int bm = blockIdx.y * 64;
    const int bn = blockIdx.x * 64;
    const int tid = threadIdx.x;
    const int tr = tid >> 4;
    const int tc = tid & 15;
    const int lar = tid >> 2;
    const int lac = (tid & 3) << 2;
    const int lbr = tid >> 4;
    const int lbc = (tid & 15) << 2;

    float acc[4][4] = {};
    const int arow = min(bm + lar, M - 1);

    for (int k0 = 0; k0 < K; k0 += 16) {
        const float4 av = *(const float4*)&A[(size_t)arow * K + k0 + lac];
        const float4 bv = *(const float4*)&B[(size_t)(k0 + lbr) * N + bn + lbc];
        __syncthreads();
        As[lac + 0][lar] = av.x;
        As[lac + 1][lar] = av.y;
        As[lac + 2][lar] = av.z;
        As[lac + 3][lar] = av.w;
        *(float4*)&Bs[lbr][lbc] = bv;
        __syncthreads();
#pragma unroll
        for (int k = 0; k < 16; ++k) {
            float a[4], b[4];
            *(float4*)a = *(const float4*)&As[k][tr << 2];
            *(float4*)b = *(const float4*)&Bs[k][tc << 2];
#pragma unroll
            for (int i = 0; i < 4; ++i)
#pragma unroll
                for (int j = 0; j < 4; ++j)
                    acc[i][j] = fmaf(a[i], b[j], acc[i][j]);
        }
    }

#pragma unroll
    for (int i = 0; i < 4; ++i) {
        const int row = bm + (tr << 2) + i;
        if (row < M) {
#pragma unroll
            for (int j = 0; j < 4; ++j) {
                const int col = bn + (tc << 2) + j;
                float v = acc[i][j] + bias[col];
                if (ACT) v = silu_f(v);
                C[(size_t)row * N + col] = v;
            }
        }
    }
}

// ---------------------------------------------------------------------------
__global__ void init_ns_kernel(const int* __restrict__ Z,
                               const float* __restrict__ embed,
                               float* __restrict__ ns, int n_atoms)
{
    int i = blockIdx.x * 256 + threadIdx.x;
    if (i >= n_atoms * FDIM) return;
    int a = i >> 8, f = i & 255;
    ns[i] = embed[Z[a] * FDIM + f];
}

// ---------------------------------------------------------------------------
// Counting sort of edges by recv atom.
// ---------------------------------------------------------------------------
__global__ void hist_kernel(const int* __restrict__ edge, int* __restrict__ counts,
                            int n_edges)
{
    int e = blockIdx.x * 256 + threadIdx.x;
    if (e >= n_edges) return;
    atomicAdd(&counts[edge[2 * e]], 1);
}

// single block, 256 threads, each owns 20 contiguous bins
__global__ __launch_bounds__(256)
void scan_kernel(const int* __restrict__ counts, int* __restrict__ start,
                 int* __restrict__ cursor, int n)
{
    __shared__ int sums[256];
    const int t = threadIdx.x;
    const int base = t * 20;
    int local[20];
    int s = 0;
#pragma unroll
    for (int i = 0; i < 20; ++i) {
        int c = (base + i < n) ? counts[base + i] : 0;
        local[i] = s;
        s += c;
    }
    sums[t] = s;
    __syncthreads();
    for (int off = 1; off < 256; off <<= 1) {
        int v = (t >= off) ? sums[t - off] : 0;
        __syncthreads();
        sums[t] += v;
        __syncthreads();
    }
    const int pre = (t > 0) ? sums[t - 1] : 0;
#pragma unroll
    for (int i = 0; i < 20; ++i) {
        if (base + i < n) {
            start[base + i] = pre + local[i];
            cursor[base + i] = pre + local[i];
        }
    }
    if (t == 255) start[n] = sums[255];
}

__global__ void scatter_kernel(const int* __restrict__ edge,
                               const float* __restrict__ edge_diff,
                               const float* __restrict__ edge_dist,
                               int* __restrict__ cursor,
                               int* __restrict__ ssend,
                               float4* __restrict__ sgeo,
                               int n_edges)
{
    int e = blockIdx.x * 256 + threadIdx.x;
    if (e >= n_edges) return;
    const int recv = edge[2 * e + 0];
    const int send = edge[2 * e + 1];
    const int pos = atomicAdd(&cursor[recv], 1);
    const float dist = edge_dist[e];
    const float inv = 1.0f / dist;
    float4 g;
    g.x = edge_diff[3 * e + 0] * inv;
    g.y = edge_diff[3 * e + 1] * inv;
    g.z = edge_diff[3 * e + 2] * inv;
    g.w = dist;
    ssend[pos] = send;
    sgeo[pos] = g;
}

// ---------------------------------------------------------------------------
// Per-atom message aggregation (atomic-free). One block (256 thr) per atom.
// Thread f owns filter-weight columns f, f+256, f+512 in registers.
// ---------------------------------------------------------------------------
__global__ __launch_bounds__(256)
void agg_kernel(const int* __restrict__ start,
                const int* __restrict__ ssend,
                const float4* __restrict__ sgeo,
                const float* __restrict__ wf,    // (20,768) this layer
                const float* __restrict__ bf,    // (768)
                const float* __restrict__ so,    // (n_atoms,768)
                const float* __restrict__ nv_old,// (n_atoms,3,256)
                float* __restrict__ ns,          // += msg_s
                float* __restrict__ nv_new,      // = nv_old + sum(msg_v)
                int n_atoms)
{
    const int f = threadIdx.x;
    const int a = blockIdx.x;
    float w0[NBF], w1[NBF], w2[NBF];
#pragma unroll
    for (int k = 0; k < NBF; ++k) {
        w0[k] = wf[k * 768 + f];
        w1[k] = wf[k * 768 + 256 + f];
        w2[k] = wf[k * 768 + 512 + f];
    }
    const float b0 = bf[f], b1 = bf[256 + f], b2 = bf[512 + f];

    float accs = 0.0f, av0 = 0.0f, av1 = 0.0f, av2 = 0.0f;
    const int i0 = start[a], i1 = start[a + 1];
    for (int i = i0; i < i1; ++i) {
        const int send = ssend[i];
        const float4 g = sgeo[i];
        const float dist = g.w;
        const float inv = 1.0f / dist;
        const float fcut = (dist < 5.0f)
            ? 0.5f * (__cosf(dist * (PI_F / 5.0f)) + 1.0f) : 0.0f;

        float f0 = b0, f1 = b1, f2 = b2;
#pragma unroll
        for (int k = 0; k < NBF; ++k) {
            const float r = __sinf(dist * ((k + 1) * (PI_F / 5.0f))) * inv;
            f0 = fmaf(r, w0[k], f0);
            f1 = fmaf(r, w1[k], f1);
            f2 = fmaf(r, w2[k], f2);
        }
        f0 *= fcut; f1 *= fcut; f2 *= fcut;

        const float* sp = so + (size_t)send * 768;
        const float gv = f0 * sp[f];
        const float ge = f1 * sp[256 + f];
        const float ms = f2 * sp[512 + f];
        accs += ms;

        const float* nvp = nv_old + (size_t)send * 768;
        av0 += fmaf(nvp[f],       gv, g.x * ge);
        av1 += fmaf(nvp[256 + f], gv, g.y * ge);
        av2 += fmaf(nvp[512 + f], gv, g.z * ge);
    }

    ns[(size_t)a * 256 + f] += accs;
    const size_t b = (size_t)a * 768 + f;
    nv_new[b]       = nv_old[b]       + av0;
    nv_new[b + 256] = nv_old[b + 256] + av1;
    nv_new[b + 512] = nv_old[b + 512] + av2;
}

// ---------------------------------------------------------------------------
__global__ void vncat_kernel(const float* __restrict__ Vv,
                             const float* __restrict__ ns,
                             float* __restrict__ cat, int n_atoms)
{
    int i = blockIdx.x * 256 + threadIdx.x;
    if (i >= n_atoms * FDIM) return;
    int a = i >> 8, f = i & 255;
    const float v0 = Vv[(size_t)a * 768 + f];
    const float v1 = Vv[(size_t)a * 768 + 256 + f];
    const float v2 = Vv[(size_t)a * 768 + 512 + f];
    cat[(size_t)a * 512 + f] = sqrtf(v0 * v0 + v1 * v1 + v2 * v2);
    cat[(size_t)a * 512 + 256 + f] = ns[i];
}

// ---------------------------------------------------------------------------
__global__ void apply_update_kernel(const float* __restrict__ mlp,
                                    const float* __restrict__ Uv,
                                    const float* __restrict__ Vv,
                                    float* __restrict__ nv,
                                    float* __restrict__ ns, int n_atoms)
{
    int i = blockIdx.x * 256 + threadIdx.x;
    if (i >= n_atoms * FDIM) return;
    int a = i >> 8, f = i & 255;
    const float avv = mlp[(size_t)a * 768 + f];
    const float asv = mlp[(size_t)a * 768 + 256 + f];
    const float ass = mlp[(size_t)a * 768 + 512 + f];
    float dot = 0.0f;
#pragma unroll
    for (int d = 0; d < 3; ++d) {
        const size_t idx = (size_t)a * 768 + d * 256 + f;
        const float u = Uv[idx];
        const float v = Vv[idx];
        nv[idx] = fmaf(avv, u, nv[idx]);
        dot = fmaf(u, v, dot);
    }
    ns[i] = ns[i] + fmaf(asv, dot, ass);
}

// ---------------------------------------------------------------------------
__global__ void readout_kernel(const float* __restrict__ hid,
                               const float* __restrict__ w2,
                               const float* __restrict__ b2,
                               float* __restrict__ out, int n_atoms)
{
    const int a = blockIdx.x;
    const int lane = threadIdx.x; // 64
    const float* h = hid + (size_t)a * FDIM;
    float s = 0.0f;
#pragma unroll
    for (int i = 0; i < 4; ++i)
        s += h[lane + 64 * i] * w2[lane + 64 * i];
#pragma unroll
    for (int off = 32; off > 0; off >>= 1)
        s += __shfl_down(s, off);
    if (lane == 0) out[a] = s + b2[0];
}

// ---------------------------------------------------------------------------
static inline void launch_gemm(int act, const float* A, const float* B,
                               const float* bias, float* C,
                               int M, int N, int K, hipStream_t s)
{
    dim3 grid(N / 64, (M + 63) / 64);
    if (act)
        gemm_kernel<1><<<grid, 256, 0, s>>>(A, B, bias, C, M, N, K);
    else
        gemm_kernel<0><<<grid, 256, 0, s>>>(A, B, bias, C, M, N, K);
}

extern "C" void kernel_launch(void* const* d_in, const int* in_sizes, int n_in,
                              void* d_out, int out_size, void* d_ws, size_t ws_size,
                              hipStream_t stream)
{
    const int*   Z            = (const int*)  d_in[0];
    const int*   edge         = (const int*)  d_in[1];
    const float* edge_diff    = (const float*)d_in[2];
    const float* edge_dist    = (const float*)d_in[3];
    const float* embed        = (const float*)d_in[4];
    const float* msg_w_filter = (const float*)d_in[5];
    const float* msg_b_filter = (const float*)d_in[6];
    const float* msg_w1       = (const float*)d_in[7];
    const float* msg_b1       = (const float*)d_in[8];
    const float* msg_w2       = (const float*)d_in[9];
    const float* msg_b2       = (const float*)d_in[10];
    const float* upd_wU       = (const float*)d_in[11];
    const float* upd_bU       = (const float*)d_in[12];
    const float* upd_wV       = (const float*)d_in[13];
    const float* upd_bV       = (const float*)d_in[14];
    const float* upd_w1       = (const float*)d_in[15];
    const float* upd_b1       = (const float*)d_in[16];
    const float* upd_w2       = (const float*)d_in[17];
    const float* upd_b2       = (const float*)d_in[18];
    const float* ro_w1        = (const float*)d_in[19];
    const float* ro_b1        = (const float*)d_in[20];
    const float* ro_w2        = (const float*)d_in[21];
    const float* ro_b2        = (const float*)d_in[22];
    float* out = (float*)d_out;

    const int n_atoms = in_sizes[0];
    const int n_edges = in_sizes[1] / 2;

    float* p   = (float*)d_ws;
    float* ns  = p; p += (size_t)n_atoms * 256;
    float* nvA = p; p += (size_t)n_atoms * 768;
    float* nvB = p; p += (size_t)n_atoms * 768;
    float* so  = p; p += (size_t)n_atoms * 768;
    float* hid = p; p += (size_t)n_atoms * 256;
    float* Uv  = p; p += (size_t)n_atoms * 768;
    float* Vv  = p; p += (size_t)n_atoms * 768;
    float* cat = p; p += (size_t)n_atoms * 512;
    int*   counts = (int*)p;   p += n_atoms;
    int*   cursor = (int*)p;   p += n_atoms;
    int*   start  = (int*)p;   p += n_atoms + 4;
    int*   ssend  = (int*)p;   p += n_edges;
    // align to 16B for float4
    float4* sgeo = (float4*)((((uintptr_t)p) + 15) & ~(uintptr_t)15);

    // ---- edge sort by recv (layer-invariant) ----
    hipMemsetAsync(counts, 0, n_atoms * sizeof(int), stream);
    hist_kernel<<<(n_edges + 255) / 256, 256, 0, stream>>>(edge, counts, n_edges);
    scan_kernel<<<1, 256, 0, stream>>>(counts, start, cursor, n_atoms);
    scatter_kernel<<<(n_edges + 255) / 256, 256, 0, stream>>>(
        edge, edge_diff, edge_dist, cursor, ssend, sgeo, n_edges);

    hipMemsetAsync(nvA, 0, (size_t)n_atoms * 768 * sizeof(float), stream);
    init_ns_kernel<<<(n_atoms * 256 + 255) / 256, 256, 0, stream>>>(Z, embed, ns, n_atoms);

    float* nv_old = nvA;
    float* nv_new = nvB;

    for (int l = 0; l < 3; ++l) {
        launch_gemm(1, ns, msg_w1 + (size_t)l * 256 * 256, msg_b1 + l * 256,
                    hid, n_atoms, 256, 256, stream);
        launch_gemm(0, hid, msg_w2 + (size_t)l * 256 * 768, msg_b2 + l * 768,
                    so, n_atoms, 768, 256, stream);

        agg_kernel<<<n_atoms, 256, 0, stream>>>(
            start, ssend, sgeo,
            msg_w_filter + (size_t)l * NBF * 768, msg_b_filter + l * 768,
            so, nv_old, ns, nv_new, n_atoms);

        launch_gemm(0, nv_new, upd_wU + (size_t)l * 256 * 256, upd_bU + l * 256,
                    Uv, n_atoms * 3, 256, 256, stream);
        launch_gemm(0, nv_new, upd_wV + (size_t)l * 256 * 256, upd_bV + l * 256,
                    Vv, n_atoms * 3, 256, 256, stream);

        vncat_kernel<<<(n_atoms * 256 + 255) / 256, 256, 0, stream>>>(Vv, ns, cat, n_atoms);

        launch_gemm(1, cat, upd_w1 + (size_t)l * 512 * 256, upd_b1 + l * 256,
                    hid, n_atoms, 256, 512, stream);
        launch_gemm(0, hid, upd_w2 + (size_t)l * 256 * 768, upd_b2 + l * 768,
                    so, n_atoms, 768, 256, stream);

        apply_update_kernel<<<(n_atoms * 256 + 255) / 256, 256, 0, stream>>>(
            so, Uv, Vv, nv_new, ns, n_atoms);

        float* t = nv_old; nv_old = nv_new; nv_new = t;
    }

    launch_gemm(1, ns, ro_w1, ro_b1, hid, n_atoms, 256, 256, stream);
    readout_kernel<<<n_atoms, 64, 0, stream>>>(hid, ro_w2, ro_b2, out, n_atoms);
}

// Round 4
// 1335.576 us; speedup vs baseline: 2.3861x; 1.3344x over previous
//
#include <hip/hip_runtime.h>
#include <math.h>

#define FDIM 256
#define NBF 20
#define PI_F 3.14159265358979323846f

__device__ __forceinline__ float silu_f(float x) {
    return x / (1.0f + __expf(-x));
}
__device__ __forceinline__ unsigned short f2bf(float f) {
    unsigned int x = __float_as_uint(f);
    unsigned int r = (x + 0x7fffu + ((x >> 16) & 1u)) >> 16;
    return (unsigned short)r;
}
__device__ __forceinline__ float bf2f(unsigned short u) {
    return __uint_as_float(((unsigned int)u) << 16);
}

// ---------------------------------------------------------------------------
// Tiled fp32 GEMM: C = act(A(MxK) @ B(KxN) + bias(N)) ; ACT=1 -> SiLU
// ---------------------------------------------------------------------------
template<int ACT>
__global__ __launch_bounds__(256)
void gemm_kernel(const float* __restrict__ A, const float* __restrict__ B,
                 const float* __restrict__ bias, float* __restrict__ C,
                 int M, int N, int K)
{
    __shared__ float As[16][68];
    __shared__ float Bs[16][64];

    const int bm = blockIdx.y * 64;
    const int bn = blockIdx.x * 64;
    const int tid = threadIdx.x;
    const int tr = tid >> 4;
    const int tc = tid & 15;
    const int lar = tid >> 2;
    const int lac = (tid & 3) << 2;
    const int lbr = tid >> 4;
    const int lbc = (tid & 15) << 2;

    float acc[4][4] = {};
    const int arow = min(bm + lar, M - 1);

    for (int k0 = 0; k0 < K; k0 += 16) {
        const float4 av = *(const float4*)&A[(size_t)arow * K + k0 + lac];
        const float4 bv = *(const float4*)&B[(size_t)(k0 + lbr) * N + bn + lbc];
        __syncthreads();
        As[lac + 0][lar] = av.x;
        As[lac + 1][lar] = av.y;
        As[lac + 2][lar] = av.z;
        As[lac + 3][lar] = av.w;
        *(float4*)&Bs[lbr][lbc] = bv;
        __syncthreads();
#pragma unroll
        for (int k = 0; k < 16; ++k) {
            float a[4], b[4];
            *(float4*)a = *(const float4*)&As[k][tr << 2];
            *(float4*)b = *(const float4*)&Bs[k][tc << 2];
#pragma unroll
            for (int i = 0; i < 4; ++i)
#pragma unroll
                for (int j = 0; j < 4; ++j)
                    acc[i][j] = fmaf(a[i], b[j], acc[i][j]);
        }
    }

#pragma unroll
    for (int i = 0; i < 4; ++i) {
        const int row = bm + (tr << 2) + i;
        if (row < M) {
#pragma unroll
            for (int j = 0; j < 4; ++j) {
                const int col = bn + (tc << 2) + j;
                float v = acc[i][j] + bias[col];
                if (ACT) v = silu_f(v);
                C[(size_t)row * N + col] = v;
            }
        }
    }
}

// ---------------------------------------------------------------------------
__global__ void init_ns_kernel(const int* __restrict__ Z,
                               const float* __restrict__ embed,
                               float* __restrict__ ns, int n_atoms)
{
    int i = blockIdx.x * 256 + threadIdx.x;
    if (i >= n_atoms * FDIM) return;
    int a = i >> 8, f = i & 255;
    ns[i] = embed[Z[a] * FDIM + f];
}

// float -> bf16 conversion (4 elems/thread)
__global__ void f2bf_kernel(const float* __restrict__ in,
                            unsigned short* __restrict__ out, int n)
{
    int i = (blockIdx.x * 256 + threadIdx.x) * 4;
    if (i + 3 < n) {
        const float4 v = *(const float4*)&in[i];
        ushort4 o;
        o.x = f2bf(v.x); o.y = f2bf(v.y); o.z = f2bf(v.z); o.w = f2bf(v.w);
        *(ushort4*)&out[i] = o;
    } else {
        for (; i < n; ++i) out[i] = f2bf(in[i]);
    }
}

// ---------------------------------------------------------------------------
// Counting sort of edges by recv atom.
// ---------------------------------------------------------------------------
__global__ void hist_kernel(const int* __restrict__ edge, int* __restrict__ counts,
                            int n_edges)
{
    int e = blockIdx.x * 256 + threadIdx.x;
    if (e >= n_edges) return;
    atomicAdd(&counts[edge[2 * e]], 1);
}

// single block, 256 threads, each owns 20 contiguous bins
__global__ __launch_bounds__(256)
void scan_kernel(const int* __restrict__ counts, int* __restrict__ start,
                 int* __restrict__ cursor, int n)
{
    __shared__ int sums[256];
    const int t = threadIdx.x;
    const int base = t * 20;
    int local[20];
    int s = 0;
#pragma unroll
    for (int i = 0; i < 20; ++i) {
        int c = (base + i < n) ? counts[base + i] : 0;
        local[i] = s;
        s += c;
    }
    sums[t] = s;
    __syncthreads();
    for (int off = 1; off < 256; off <<= 1) {
        int v = (t >= off) ? sums[t - off] : 0;
        __syncthreads();
        sums[t] += v;
        __syncthreads();
    }
    const int pre = (t > 0) ? sums[t - 1] : 0;
#pragma unroll
    for (int i = 0; i < 20; ++i) {
        if (base + i < n) {
            start[base + i] = pre + local[i];
            cursor[base + i] = pre + local[i];
        }
    }
    if (t == 255) start[n] = sums[255];
}

// Scatter edges into recv-sorted order; precompute unit vec, fcut, and
// the 20 RBF values (already multiplied by fcut).
__global__ void scatter_kernel(const int* __restrict__ edge,
                               const float* __restrict__ edge_diff,
                               const float* __restrict__ edge_dist,
                               int* __restrict__ cursor,
                               int* __restrict__ ssend,
                               float4* __restrict__ sgeo,
                               float* __restrict__ srbf,
                               int n_edges)
{
    int e = blockIdx.x * 256 + threadIdx.x;
    if (e >= n_edges) return;
    const int recv = edge[2 * e + 0];
    const int send = edge[2 * e + 1];
    const int pos = atomicAdd(&cursor[recv], 1);
    const float dist = edge_dist[e];
    const float inv = 1.0f / dist;
    const float fcut = (dist < 5.0f)
        ? 0.5f * (__cosf(dist * (PI_F / 5.0f)) + 1.0f) : 0.0f;
    float4 g;
    g.x = edge_diff[3 * e + 0] * inv;
    g.y = edge_diff[3 * e + 1] * inv;
    g.z = edge_diff[3 * e + 2] * inv;
    g.w = fcut;
    ssend[pos] = send;
    sgeo[pos] = g;
    float* rp = srbf + (size_t)pos * NBF;
    const float sc = fcut * inv;
#pragma unroll
    for (int k = 0; k < NBF; ++k)
        rp[k] = __sinf(dist * ((k + 1) * (PI_F / 5.0f))) * sc;
}

// ---------------------------------------------------------------------------
// Per-atom message aggregation. One block (256 thr) per atom.
// Thread f owns filter-weight columns f, f+256, f+512 in registers.
// No transcendentals: rbf precomputed; gathers from bf16 tables.
// ---------------------------------------------------------------------------
__global__ __launch_bounds__(256, 2)
void agg_kernel(const int* __restrict__ start,
                const int* __restrict__ ssend,
                const float4* __restrict__ sgeo,
                const float* __restrict__ srbf,
                const float* __restrict__ wf,    // (20,768) this layer
                const float* __restrict__ bf,    // (768)
                const unsigned short* __restrict__ so16,  // (n_atoms,768) bf16
                const unsigned short* __restrict__ nv16,  // (n_atoms,768) bf16
                const float* __restrict__ nv_old,// (n_atoms,3,256) fp32
                float* __restrict__ ns,          // += msg_s
                float* __restrict__ nv_new,      // = nv_old + sum(msg_v)
                int n_atoms)
{
    const int f = threadIdx.x;
    const int a = blockIdx.x;
    float w0[NBF], w1[NBF], w2[NBF];
#pragma unroll
    for (int k = 0; k < NBF; ++k) {
        w0[k] = wf[k * 768 + f];
        w1[k] = wf[k * 768 + 256 + f];
        w2[k] = wf[k * 768 + 512 + f];
    }
    const float b0 = bf[f], b1 = bf[256 + f], b2 = bf[512 + f];

    float accs = 0.0f, av0 = 0.0f, av1 = 0.0f, av2 = 0.0f;
    const int i0 = start[a], i1 = start[a + 1];
    for (int i = i0; i < i1; ++i) {
        const int send = ssend[i];
        const float4 g = sgeo[i];
        float r[NBF];
        {
            const float4* rp = (const float4*)(srbf + (size_t)i * NBF);
#pragma unroll
            for (int q = 0; q < NBF / 4; ++q)
                *(float4*)&r[q * 4] = rp[q];
        }
        // filt = fcut*b + sum_k rbf_k * W_k   (rbf already includes fcut)
        float f0 = g.w * b0, f1 = g.w * b1, f2 = g.w * b2;
#pragma unroll
        for (int k = 0; k < NBF; ++k) {
            f0 = fmaf(r[k], w0[k], f0);
            f1 = fmaf(r[k], w1[k], f1);
            f2 = fmaf(r[k], w2[k], f2);
        }

        const unsigned short* sp = so16 + (size_t)send * 768;
        const float gv = f0 * bf2f(sp[f]);
        const float ge = f1 * bf2f(sp[256 + f]);
        const float ms = f2 * bf2f(sp[512 + f]);
        accs += ms;

        const unsigned short* nvp = nv16 + (size_t)send * 768;
        av0 += fmaf(bf2f(nvp[f]),       gv, g.x * ge);
        av1 += fmaf(bf2f(nvp[256 + f]), gv, g.y * ge);
        av2 += fmaf(bf2f(nvp[512 + f]), gv, g.z * ge);
    }

    ns[(size_t)a * 256 + f] += accs;
    const size_t b = (size_t)a * 768 + f;
    nv_new[b]       = nv_old[b]       + av0;
    nv_new[b + 256] = nv_old[b + 256] + av1;
    nv_new[b + 512] = nv_old[b + 512] + av2;
}

// ---------------------------------------------------------------------------
__global__ void vncat_kernel(const float* __restrict__ Vv,
                             const float* __restrict__ ns,
                             float* __restrict__ cat, int n_atoms)
{
    int i = blockIdx.x * 256 + threadIdx.x;
    if (i >= n_atoms * FDIM) return;
    int a = i >> 8, f = i & 255;
    const float v0 = Vv[(size_t)a * 768 + f];
    const float v1 = Vv[(size_t)a * 768 + 256 + f];
    const float v2 = Vv[(size_t)a * 768 + 512 + f];
    cat[(size_t)a * 512 + f] = sqrtf(v0 * v0 + v1 * v1 + v2 * v2);
    cat[(size_t)a * 512 + 256 + f] = ns[i];
}

// ---------------------------------------------------------------------------
__global__ void apply_update_kernel(const float* __restrict__ mlp,
                                    const float* __restrict__ Uv,
                                    const float* __restrict__ Vv,
                                    float* __restrict__ nv,
                                    float* __restrict__ ns, int n_atoms)
{
    int i = blockIdx.x * 256 + threadIdx.x;
    if (i >= n_atoms * FDIM) return;
    int a = i >> 8, f = i & 255;
    const float avv = mlp[(size_t)a * 768 + f];
    const float asv = mlp[(size_t)a * 768 + 256 + f];
    const float ass = mlp[(size_t)a * 768 + 512 + f];
    float dot = 0.0f;
#pragma unroll
    for (int d = 0; d < 3; ++d) {
        const size_t idx = (size_t)a * 768 + d * 256 + f;
        const float u = Uv[idx];
        const float v = Vv[idx];
        nv[idx] = fmaf(avv, u, nv[idx]);
        dot = fmaf(u, v, dot);
    }
    ns[i] = ns[i] + fmaf(asv, dot, ass);
}

// ---------------------------------------------------------------------------
__global__ void readout_kernel(const float* __restrict__ hid,
                               const float* __restrict__ w2,
                               const float* __restrict__ b2,
                               float* __restrict__ out, int n_atoms)
{
    const int a = blockIdx.x;
    const int lane = threadIdx.x; // 64
    const float* h = hid + (size_t)a * FDIM;
    float s = 0.0f;
#pragma unroll
    for (int i = 0; i < 4; ++i)
        s += h[lane + 64 * i] * w2[lane + 64 * i];
#pragma unroll
    for (int off = 32; off > 0; off >>= 1)
        s += __shfl_down(s, off);
    if (lane == 0) out[a] = s + b2[0];
}

// ---------------------------------------------------------------------------
static inline void launch_gemm(int act, const float* A, const float* B,
                               const float* bias, float* C,
                               int M, int N, int K, hipStream_t s)
{
    dim3 grid(N / 64, (M + 63) / 64);
    if (act)
        gemm_kernel<1><<<grid, 256, 0, s>>>(A, B, bias, C, M, N, K);
    else
        gemm_kernel<0><<<grid, 256, 0, s>>>(A, B, bias, C, M, N, K);
}

extern "C" void kernel_launch(void* const* d_in, const int* in_sizes, int n_in,
                              void* d_out, int out_size, void* d_ws, size_t ws_size,
                              hipStream_t stream)
{
    const int*   Z            = (const int*)  d_in[0];
    const int*   edge         = (const int*)  d_in[1];
    const float* edge_diff    = (const float*)d_in[2];
    const float* edge_dist    = (const float*)d_in[3];
    const float* embed        = (const float*)d_in[4];
    const float* msg_w_filter = (const float*)d_in[5];
    const float* msg_b_filter = (const float*)d_in[6];
    const float* msg_w1       = (const float*)d_in[7];
    const float* msg_b1       = (const float*)d_in[8];
    const float* msg_w2       = (const float*)d_in[9];
    const float* msg_b2       = (const float*)d_in[10];
    const float* upd_wU       = (const float*)d_in[11];
    const float* upd_bU       = (const float*)d_in[12];
    const float* upd_wV       = (const float*)d_in[13];
    const float* upd_bV       = (const float*)d_in[14];
    const float* upd_w1       = (const float*)d_in[15];
    const float* upd_b1       = (const float*)d_in[16];
    const float* upd_w2       = (const float*)d_in[17];
    const float* upd_b2       = (const float*)d_in[18];
    const float* ro_w1        = (const float*)d_in[19];
    const float* ro_b1        = (const float*)d_in[20];
    const float* ro_w2        = (const float*)d_in[21];
    const float* ro_b2        = (const float*)d_in[22];
    float* out = (float*)d_out;

    const int n_atoms = in_sizes[0];
    const int n_edges = in_sizes[1] / 2;

    float* p   = (float*)d_ws;
    float* ns  = p; p += (size_t)n_atoms * 256;
    float* nvA = p; p += (size_t)n_atoms * 768;
    float* nvB = p; p += (size_t)n_atoms * 768;
    float* so  = p; p += (size_t)n_atoms * 768;
    float* hid = p; p += (size_t)n_atoms * 256;
    float* Uv  = p; p += (size_t)n_atoms * 768;
    float* Vv  = p; p += (size_t)n_atoms * 768;
    float* cat = so; // alias: `so` is dead between agg and the upd_w2 GEMM
    unsigned short* so16 = (unsigned short*)p; p += (size_t)n_atoms * 384;
    unsigned short* nv16 = (unsigned short*)p; p += (size_t)n_atoms * 384;
    int*   counts = (int*)p;   p += n_atoms;
    int*   cursor = (int*)p;   p += n_atoms;
    int*   start  = (int*)p;   p += n_atoms + 4;
    int*   ssend  = (int*)p;   p += n_edges;
    float* srbf   = p;         p += (size_t)n_edges * NBF;
    float4* sgeo = (float4*)((((uintptr_t)p) + 15) & ~(uintptr_t)15);

    // ---- edge sort by recv + RBF precompute (layer-invariant) ----
    hipMemsetAsync(counts, 0, n_atoms * sizeof(int), stream);
    hist_kernel<<<(n_edges + 255) / 256, 256, 0, stream>>>(edge, counts, n_edges);
    scan_kernel<<<1, 256, 0, stream>>>(counts, start, cursor, n_atoms);
    scatter_kernel<<<(n_edges + 255) / 256, 256, 0, stream>>>(
        edge, edge_diff, edge_dist, cursor, ssend, sgeo, srbf, n_edges);

    hipMemsetAsync(nvA, 0, (size_t)n_atoms * 768 * sizeof(float), stream);
    init_ns_kernel<<<(n_atoms * 256 + 255) / 256, 256, 0, stream>>>(Z, embed, ns, n_atoms);

    float* nv_old = nvA;
    float* nv_new = nvB;
    const int nconv = n_atoms * 768;
    const int convblocks = (nconv / 4 + 255) / 256;

    for (int l = 0; l < 3; ++l) {
        launch_gemm(1, ns, msg_w1 + (size_t)l * 256 * 256, msg_b1 + l * 256,
                    hid, n_atoms, 256, 256, stream);
        launch_gemm(0, hid, msg_w2 + (size_t)l * 256 * 768, msg_b2 + l * 768,
                    so, n_atoms, 768, 256, stream);

        // bf16 gather tables for this layer
        f2bf_kernel<<<convblocks, 256, 0, stream>>>(so, so16, nconv);
        f2bf_kernel<<<convblocks, 256, 0, stream>>>(nv_old, nv16, nconv);

        agg_kernel<<<n_atoms, 256, 0, stream>>>(
            start, ssend, sgeo, srbf,
            msg_w_filter + (size_t)l * NBF * 768, msg_b_filter + l * 768,
            so16, nv16, nv_old, ns, nv_new, n_atoms);

        launch_gemm(0, nv_new, upd_wU + (size_t)l * 256 * 256, upd_bU + l * 256,
                    Uv, n_atoms * 3, 256, 256, stream);
        launch_gemm(0, nv_new, upd_wV + (size_t)l * 256 * 256, upd_bV + l * 256,
                    Vv, n_atoms * 3, 256, 256, stream);

        vncat_kernel<<<(n_atoms * 256 + 255) / 256, 256, 0, stream>>>(Vv, ns, cat, n_atoms);

        launch_gemm(1, cat, upd_w1 + (size_t)l * 512 * 256, upd_b1 + l * 256,
                    hid, n_atoms, 256, 512, stream);
        launch_gemm(0, hid, upd_w2 + (size_t)l * 256 * 768, upd_b2 + l * 768,
                    so, n_atoms, 768, 256, stream);

        apply_update_kernel<<<(n_atoms * 256 + 255) / 256, 256, 0, stream>>>(
            so, Uv, Vv, nv_new, ns, n_atoms);

        float* t = nv_old; nv_old = nv_new; nv_new = t;
    }

    launch_gemm(1, ns, ro_w1, ro_b1, hid, n_atoms, 256, 256, stream);
    readout_kernel<<<n_atoms, 64, 0, stream>>>(hid, ro_w2, ro_b2, out, n_atoms);
}

// Round 6
// 1191.988 us; speedup vs baseline: 2.6735x; 1.1205x over previous
//
#include <hip/hip_runtime.h>
#include <math.h>

#define FDIM 256
#define NBF 20
#define PI_F 3.14159265358979323846f

typedef __attribute__((ext_vector_type(8))) short short8;
typedef __attribute__((ext_vector_type(4))) float f32x4;

__device__ __forceinline__ float silu_f(float x) {
    return x / (1.0f + __expf(-x));
}
__device__ __forceinline__ unsigned short f2bf(float f) {
    unsigned int x = __float_as_uint(f);
    unsigned int r = (x + 0x7fffu + ((x >> 16) & 1u)) >> 16;
    return (unsigned short)r;
}
__device__ __forceinline__ float bf2f(unsigned short u) {
    return __uint_as_float(((unsigned int)u) << 16);
}

// ---------------------------------------------------------------------------
// Split-bf16 MFMA GEMM (~fp32 accuracy): C = act(A_f32 @ B + bias)
// B pre-split transposed: Bh,Bl are (N,K) bf16; B ~= Bh + Bl (16 mantissa bits).
// A split to hi/lo bf16 in-kernel during staging.
// acc = Ah*Bh + Ah*Bl + Al*Bh  (Al*Bl ~ 2^-18, dropped)
// BM=BN=128, BK=32, 256 thr (4 waves 2x2 of 64x64), 4x4 frags.
// N must be multiple of 128. OUTBF: write bf16, else f32.
// ---------------------------------------------------------------------------
template<int ACT, int OUTBF>
__global__ __launch_bounds__(256)
void mgemm_kernel(const float* __restrict__ A,
                  const unsigned short* __restrict__ Bh,
                  const unsigned short* __restrict__ Bl,
                  const float* __restrict__ bias,
                  void* __restrict__ Cout,
                  int M, int N, int K)
{
    __shared__ unsigned short As_hi[128][40];
    __shared__ unsigned short As_lo[128][40];
    __shared__ unsigned short Bs_hi[128][40];
    __shared__ unsigned short Bs_lo[128][40];

    const int bm = blockIdx.y * 128;
    const int bn = blockIdx.x * 128;
    const int tid = threadIdx.x;
    const int wid = tid >> 6;
    const int lane = tid & 63;
    const int wr = (wid >> 1) * 64;
    const int wc = (wid & 1) * 64;
    const int r16 = lane & 15;
    const int kg  = lane >> 4;

    f32x4 acc[4][4];
#pragma unroll
    for (int i = 0; i < 4; ++i)
#pragma unroll
        for (int j = 0; j < 4; ++j)
            acc[i][j] = (f32x4){0.f, 0.f, 0.f, 0.f};

    const int sr = tid >> 1;            // staging row 0..127
    const int cb = (tid & 1) * 16;      // staging col base 0/16

    for (int k0 = 0; k0 < K; k0 += 32) {
        __syncthreads();
        // ---- stage A (fp32 -> hi/lo bf16) ----
        {
            const int gr = min(bm + sr, M - 1);
            const float* ap = &A[(size_t)gr * K + k0 + cb];
            short8 hv[2], lv[2];
#pragma unroll
            for (int q = 0; q < 4; ++q) {
                const float4 v = *(const float4*)(ap + q * 4);
                const float xs[4] = {v.x, v.y, v.z, v.w};
#pragma unroll
                for (int j = 0; j < 4; ++j) {
                    const int idx = q * 4 + j;
                    const unsigned short hh = f2bf(xs[j]);
                    hv[idx >> 3][idx & 7] = (short)hh;
                    lv[idx >> 3][idx & 7] = (short)f2bf(xs[j] - bf2f(hh));
                }
            }
            *(short8*)&As_hi[sr][cb]     = hv[0];
            *(short8*)&As_hi[sr][cb + 8] = hv[1];
            *(short8*)&As_lo[sr][cb]     = lv[0];
            *(short8*)&As_lo[sr][cb + 8] = lv[1];
        }
        // ---- stage B (pre-split bf16) ----
        {
            const size_t bo = (size_t)(bn + sr) * K + k0 + cb;
            *(short8*)&Bs_hi[sr][cb]     = *(const short8*)&Bh[bo];
            *(short8*)&Bs_hi[sr][cb + 8] = *(const short8*)&Bh[bo + 8];
            *(short8*)&Bs_lo[sr][cb]     = *(const short8*)&Bl[bo];
            *(short8*)&Bs_lo[sr][cb + 8] = *(const short8*)&Bl[bo + 8];
        }
        __syncthreads();

        short8 ah[4], al[4], bh4[4], bl4[4];
#pragma unroll
        for (int fr = 0; fr < 4; ++fr) {
            ah[fr] = *(const short8*)&As_hi[wr + fr * 16 + r16][kg * 8];
            al[fr] = *(const short8*)&As_lo[wr + fr * 16 + r16][kg * 8];
        }
#pragma unroll
        for (int fc = 0; fc < 4; ++fc) {
            bh4[fc] = *(const short8*)&Bs_hi[wc + fc * 16 + r16][kg * 8];
            bl4[fc] = *(const short8*)&Bs_lo[wc + fc * 16 + r16][kg * 8];
        }
#pragma unroll
        for (int fr = 0; fr < 4; ++fr)
#pragma unroll
            for (int fc = 0; fc < 4; ++fc) {
                acc[fr][fc] = __builtin_amdgcn_mfma_f32_16x16x32_bf16(
                    al[fr], bh4[fc], acc[fr][fc], 0, 0, 0);
                acc[fr][fc] = __builtin_amdgcn_mfma_f32_16x16x32_bf16(
                    ah[fr], bl4[fc], acc[fr][fc], 0, 0, 0);
                acc[fr][fc] = __builtin_amdgcn_mfma_f32_16x16x32_bf16(
                    ah[fr], bh4[fc], acc[fr][fc], 0, 0, 0);
            }
    }

    // epilogue: C/D layout col=lane&15, row=(lane>>4)*4+reg
#pragma unroll
    for (int fr = 0; fr < 4; ++fr) {
#pragma unroll
        for (int fc = 0; fc < 4; ++fc) {
            const int col = bn + wc + fc * 16 + r16;
            const int row0 = bm + wr + fr * 16 + kg * 4;
            const float bsc = bias[col];
            const f32x4 v = acc[fr][fc];
#pragma unroll
            for (int j = 0; j < 4; ++j) {
                const int row = row0 + j;
                if (row < M) {
                    float x = v[j] + bsc;
                    if (ACT) x = silu_f(x);
                    if (OUTBF)
                        ((unsigned short*)Cout)[(size_t)row * N + col] = f2bf(x);
                    else
                        ((float*)Cout)[(size_t)row * N + col] = x;
                }
            }
        }
    }
}

// ---------------------------------------------------------------------------
// Weight transpose + hi/lo bf16 split. blockIdx.z = weight id (0..18).
// dst offsets (ushort idx), Bt layout (N,K):
//   msg_w1[l] : 0       + l*65536    (256x256)
//   msg_w2[l] : 196608  + l*196608   (768x256)
//   upd_wU[l] : 786432  + l*131072   (first 256 rows of fused UV)
//   upd_wV[l] : 786432  + l*131072 + 65536
//   upd_w1[l] : 1179648 + l*131072   (256x512)
//   upd_w2[l] : 1572864 + l*196608   (768x256)
//   ro_w1     : 2162688              (256x256)
// ---------------------------------------------------------------------------
__global__ __launch_bounds__(256)
void wconv_kernel(const float* __restrict__ msg_w1, const float* __restrict__ msg_w2,
                  const float* __restrict__ upd_wU, const float* __restrict__ upd_wV,
                  const float* __restrict__ upd_w1, const float* __restrict__ upd_w2,
                  const float* __restrict__ ro_w1,
                  unsigned short* __restrict__ wTh, unsigned short* __restrict__ wTl)
{
    const int id = blockIdx.z;
    const float* src; int R, C; size_t doff;
    if (id < 18) {
        const int l = id / 6, w = id % 6;
        switch (w) {
        case 0: src = msg_w1 + (size_t)l * 65536;  R = 256; C = 256; doff = 0       + (size_t)l * 65536;  break;
        case 1: src = msg_w2 + (size_t)l * 196608; R = 256; C = 768; doff = 196608  + (size_t)l * 196608; break;
        case 2: src = upd_wU + (size_t)l * 65536;  R = 256; C = 256; doff = 786432  + (size_t)l * 131072; break;
        case 3: src = upd_wV + (size_t)l * 65536;  R = 256; C = 256; doff = 786432  + (size_t)l * 131072 + 65536; break;
        case 4: src = upd_w1 + (size_t)l * 131072; R = 512; C = 256; doff = 1179648 + (size_t)l * 131072; break;
        default: src = upd_w2 + (size_t)l * 196608; R = 256; C = 768; doff = 1572864 + (size_t)l * 196608; break;
        }
    } else { src = ro_w1; R = 256; C = 256; doff = 2162688; }

    if (blockIdx.x * 32 >= C || blockIdx.y * 32 >= R) return;

    __shared__ float t[32][33];
    const int x = threadIdx.x & 31, y4 = threadIdx.x >> 5;
    for (int yy = y4; yy < 32; yy += 8) {
        const int r = blockIdx.y * 32 + yy, c = blockIdx.x * 32 + x;
        t[yy][x] = (r < R && c < C) ? src[(size_t)r * C + c] : 0.f;
    }
    __syncthreads();
    for (int yy = y4; yy < 32; yy += 8) {
        const int c = blockIdx.x * 32 + yy, r = blockIdx.y * 32 + x;
        if (c < C && r < R) {
            const float v = t[x][yy];
            const unsigned short h = f2bf(v);
            wTh[doff + (size_t)c * R + r] = h;
            wTl[doff + (size_t)c * R + r] = f2bf(v - bf2f(h));
        }
    }
}

// biasUV[l][0:256]=upd_bU[l], [256:512]=upd_bV[l]
__global__ void biascat_kernel(const float* __restrict__ bU,
                               const float* __restrict__ bV,
                               float* __restrict__ o)
{
    int i = blockIdx.x * 256 + threadIdx.x;
    if (i >= 1536) return;
    int l = i >> 9, j = i & 511;
    o[i] = (j < 256) ? bU[l * 256 + j] : bV[l * 256 + j - 256];
}

// ---------------------------------------------------------------------------
__global__ void init_ns_kernel(const int* __restrict__ Z,
                               const float* __restrict__ embed,
                               float* __restrict__ ns, int n_atoms)
{
    int i = blockIdx.x * 256 + threadIdx.x;
    if (i >= n_atoms * FDIM) return;
    int a = i >> 8, f = i & 255;
    ns[i] = embed[Z[a] * FDIM + f];
}

// ---------------------------------------------------------------------------
// Counting sort of edges by recv atom.
// ---------------------------------------------------------------------------
__global__ void hist_kernel(const int* __restrict__ edge, int* __restrict__ counts,
                            int n_edges)
{
    int e = blockIdx.x * 256 + threadIdx.x;
    if (e >= n_edges) return;
    atomicAdd(&counts[edge[2 * e]], 1);
}

__global__ __launch_bounds__(256)
void scan_kernel(const int* __restrict__ counts, int* __restrict__ start,
                 int* __restrict__ cursor, int n)
{
    __shared__ int sums[256];
    const int t = threadIdx.x;
    const int base = t * 20;
    int local[20];
    int s = 0;
#pragma unroll
    for (int i = 0; i < 20; ++i) {
        int c = (base + i < n) ? counts[base + i] : 0;
        local[i] = s;
        s += c;
    }
    sums[t] = s;
    __syncthreads();
    for (int off = 1; off < 256; off <<= 1) {
        int v = (t >= off) ? sums[t - off] : 0;
        __syncthreads();
        sums[t] += v;
        __syncthreads();
    }
    const int pre = (t > 0) ? sums[t - 1] : 0;
#pragma unroll
    for (int i = 0; i < 20; ++i) {
        if (base + i < n) {
            start[base + i] = pre + local[i];
            cursor[base + i] = pre + local[i];
        }
    }
    if (t == 255) start[n] = sums[255];
}

__global__ void scatter_kernel(const int* __restrict__ edge,
                               const float* __restrict__ edge_diff,
                               const float* __restrict__ edge_dist,
                               int* __restrict__ cursor,
                               int* __restrict__ ssend,
                               float4* __restrict__ sgeo,
                               float* __restrict__ srbf,
                               int n_edges)
{
    int e = blockIdx.x * 256 + threadIdx.x;
    if (e >= n_edges) return;
    const int recv = edge[2 * e + 0];
    const int send = edge[2 * e + 1];
    const int pos = atomicAdd(&cursor[recv], 1);
    const float dist = edge_dist[e];
    const float inv = 1.0f / dist;
    const float fcut = (dist < 5.0f)
        ? 0.5f * (__cosf(dist * (PI_F / 5.0f)) + 1.0f) : 0.0f;
    float4 g;
    g.x = edge_diff[3 * e + 0] * inv;
    g.y = edge_diff[3 * e + 1] * inv;
    g.z = edge_diff[3 * e + 2] * inv;
    g.w = fcut;
    ssend[pos] = send;
    sgeo[pos] = g;
    float* rp = srbf + (size_t)pos * NBF;
    const float sc = fcut * inv;
#pragma unroll
    for (int k = 0; k < NBF; ++k)
        rp[k] = __sinf(dist * ((k + 1) * (PI_F / 5.0f))) * sc;
}

// ---------------------------------------------------------------------------
// Per-atom message aggregation. One block (256 thr) per atom.
// ---------------------------------------------------------------------------
__global__ __launch_bounds__(256, 2)
void agg_kernel(const int* __restrict__ start,
                const int* __restrict__ ssend,
                const float4* __restrict__ sgeo,
                const float* __restrict__ srbf,
                const float* __restrict__ wf,    // (20,768) this layer
                const float* __restrict__ bf,    // (768)
                const unsigned short* __restrict__ so16,  // (n_atoms,768) bf16
                const unsigned short* __restrict__ nv16,  // (n_atoms,768) bf16
                const float* __restrict__ nv_old,// (n_atoms,3,256) fp32
                float* __restrict__ ns,          // += msg_s
                float* __restrict__ nv_new,      // = nv_old + sum(msg_v)
                unsigned short* __restrict__ nv16n, // bf16 copy of nv_new
                int n_atoms)
{
    const int f = threadIdx.x;
    const int a = blockIdx.x;
    float w0[NBF], w1[NBF], w2[NBF];
#pragma unroll
    for (int k = 0; k < NBF; ++k) {
        w0[k] = wf[k * 768 + f];
        w1[k] = wf[k * 768 + 256 + f];
        w2[k] = wf[k * 768 + 512 + f];
    }
    const float b0 = bf[f], b1 = bf[256 + f], b2 = bf[512 + f];

    float accs = 0.0f, av0 = 0.0f, av1 = 0.0f, av2 = 0.0f;
    const int i0 = start[a], i1 = start[a + 1];
    for (int i = i0; i < i1; ++i) {
        const int send = ssend[i];
        const float4 g = sgeo[i];
        float r[NBF];
        {
            const float4* rp = (const float4*)(srbf + (size_t)i * NBF);
#pragma unroll
            for (int q = 0; q < NBF / 4; ++q)
                *(float4*)&r[q * 4] = rp[q];
        }
        float f0 = g.w * b0, f1 = g.w * b1, f2 = g.w * b2;
#pragma unroll
        for (int k = 0; k < NBF; ++k) {
            f0 = fmaf(r[k], w0[k], f0);
            f1 = fmaf(r[k], w1[k], f1);
            f2 = fmaf(r[k], w2[k], f2);
        }

        const unsigned short* sp = so16 + (size_t)send * 768;
        const float gv = f0 * bf2f(sp[f]);
        const float ge = f1 * bf2f(sp[256 + f]);
        const float ms = f2 * bf2f(sp[512 + f]);
        accs += ms;

        const unsigned short* nvp = nv16 + (size_t)send * 768;
        av0 += fmaf(bf2f(nvp[f]),       gv, g.x * ge);
        av1 += fmaf(bf2f(nvp[256 + f]), gv, g.y * ge);
        av2 += fmaf(bf2f(nvp[512 + f]), gv, g.z * ge);
    }

    ns[(size_t)a * 256 + f] += accs;
    const size_t b = (size_t)a * 768 + f;
    float nvv;
    nvv = nv_old[b]       + av0; nv_new[b]       = nvv; nv16n[b]       = f2bf(nvv);
    nvv = nv_old[b + 256] + av1; nv_new[b + 256] = nvv; nv16n[b + 256] = f2bf(nvv);
    nvv = nv_old[b + 512] + av2; nv_new[b + 512] = nvv; nv16n[b + 512] = f2bf(nvv);
}

// ---------------------------------------------------------------------------
// cat[a][0:256] = |Vv[a,:,f]| ; cat[a][256:512] = ns[a][f]
// UV layout: row (a*3+d) of 512; Uv = [0:256], Vv = [256:512]
// ---------------------------------------------------------------------------
__global__ void vncat_kernel(const float* __restrict__ UV,
                             const float* __restrict__ ns,
                             float* __restrict__ cat, int n_atoms)
{
    int i = blockIdx.x * 256 + threadIdx.x;
    if (i >= n_atoms * FDIM) return;
    int a = i >> 8, f = i & 255;
    const float v0 = UV[((size_t)a * 3 + 0) * 512 + 256 + f];
    const float v1 = UV[((size_t)a * 3 + 1) * 512 + 256 + f];
    const float v2 = UV[((size_t)a * 3 + 2) * 512 + 256 + f];
    cat[(size_t)a * 512 + f] = sqrtf(v0 * v0 + v1 * v1 + v2 * v2);
    cat[(size_t)a * 512 + 256 + f] = ns[(size_t)a * 256 + f];
}

// ---------------------------------------------------------------------------
__global__ void apply_update_kernel(const float* __restrict__ mlp,
                                    const float* __restrict__ UV,
                                    float* __restrict__ nv,
                                    float* __restrict__ ns,
                                    unsigned short* __restrict__ nv16,
                                    int n_atoms)
{
    int i = blockIdx.x * 256 + threadIdx.x;
    if (i >= n_atoms * FDIM) return;
    int a = i >> 8, f = i & 255;
    const float avv = mlp[(size_t)a * 768 + f];
    const float asv = mlp[(size_t)a * 768 + 256 + f];
    const float ass = mlp[(size_t)a * 768 + 512 + f];
    float dot = 0.0f;
#pragma unroll
    for (int d = 0; d < 3; ++d) {
        const size_t iuv = ((size_t)a * 3 + d) * 512 + f;
        const float u = UV[iuv];
        const float v = UV[iuv + 256];
        const size_t inv_ = (size_t)a * 768 + d * 256 + f;
        const float nn = fmaf(avv, u, nv[inv_]);
        nv[inv_] = nn;
        nv16[inv_] = f2bf(nn);
        dot = fmaf(u, v, dot);
    }
    const float nsv = ns[i] + fmaf(asv, dot, ass);
    ns[i] = nsv;
}

// ---------------------------------------------------------------------------
__global__ void readout_kernel(const float* __restrict__ hid,
                               const float* __restrict__ w2,
                               const float* __restrict__ b2,
                               float* __restrict__ out, int n_atoms)
{
    const int a = blockIdx.x;
    const int lane = threadIdx.x; // 64
    const float* h = hid + (size_t)a * FDIM;
    float s = 0.0f;
#pragma unroll
    for (int i = 0; i < 4; ++i)
        s += h[lane + 64 * i] * w2[lane + 64 * i];
#pragma unroll
    for (int off = 32; off > 0; off >>= 1)
        s += __shfl_down(s, off);
    if (lane == 0) out[a] = s + b2[0];
}

// ---------------------------------------------------------------------------
static inline void launch_mgemm(int act, int obf, const float* A,
                                const unsigned short* Bh, const unsigned short* Bl,
                                const float* bias, void* C,
                                int M, int N, int K, hipStream_t s)
{
    dim3 grid(N / 128, (M + 127) / 128);
    if (act) {
        if (obf) mgemm_kernel<1, 1><<<grid, 256, 0, s>>>(A, Bh, Bl, bias, C, M, N, K);
        else     mgemm_kernel<1, 0><<<grid, 256, 0, s>>>(A, Bh, Bl, bias, C, M, N, K);
    } else {
        if (obf) mgemm_kernel<0, 1><<<grid, 256, 0, s>>>(A, Bh, Bl, bias, C, M, N, K);
        else     mgemm_kernel<0, 0><<<grid, 256, 0, s>>>(A, Bh, Bl, bias, C, M, N, K);
    }
}

extern "C" void kernel_launch(void* const* d_in, const int* in_sizes, int n_in,
                              void* d_out, int out_size, void* d_ws, size_t ws_size,
                              hipStream_t stream)
{
    const int*   Z            = (const int*)  d_in[0];
    const int*   edge         = (const int*)  d_in[1];
    const float* edge_diff    = (const float*)d_in[2];
    const float* edge_dist    = (const float*)d_in[3];
    const float* embed        = (const float*)d_in[4];
    const float* msg_w_filter = (const float*)d_in[5];
    const float* msg_b_filter = (const float*)d_in[6];
    const float* msg_b1       = (const float*)d_in[8];
    const float* msg_b2       = (const float*)d_in[10];
    const float* upd_bU       = (const float*)d_in[12];
    const float* upd_bV       = (const float*)d_in[14];
    const float* upd_b1       = (const float*)d_in[16];
    const float* upd_b2       = (const float*)d_in[18];
    const float* ro_b1        = (const float*)d_in[20];
    const float* ro_w2        = (const float*)d_in[21];
    const float* ro_b2        = (const float*)d_in[22];
    float* out = (float*)d_out;

    const int n_atoms = in_sizes[0];
    const int n_edges = in_sizes[1] / 2;

    // ---- workspace layout ----
    float* p   = (float*)d_ws;
    float* ns   = p; p += (size_t)n_atoms * 256;
    float* nvA  = p; p += (size_t)n_atoms * 768;
    float* nvB  = p; p += (size_t)n_atoms * 768;
    float* s768 = p; p += (size_t)n_atoms * 768;   // cat (as Mx512) then mlp (Mx768)
    float* UV   = p; p += (size_t)n_atoms * 1536;  // fused U|V, rows = 3*n_atoms
    float* hid  = p; p += (size_t)n_atoms * 256;
    unsigned short* so16  = (unsigned short*)p;  p = (float*)(so16  + (size_t)n_atoms * 768);
    unsigned short* nv16A = (unsigned short*)p;  p = (float*)(nv16A + (size_t)n_atoms * 768);
    unsigned short* nv16B = (unsigned short*)p;  p = (float*)(nv16B + (size_t)n_atoms * 768);
    unsigned short* wTh   = (unsigned short*)p;  p = (float*)(wTh + 2228224);
    unsigned short* wTl   = (unsigned short*)p;  p = (float*)(wTl + 2228224);
    float* biasUV = p; p += 1536;
    int*   counts = (int*)p;   p += n_atoms;
    int*   cursor = (int*)p;   p += n_atoms;
    int*   startp = (int*)p;   p += n_atoms + 4;
    int*   ssend  = (int*)p;   p += n_edges;
    float* srbf = (float*)((((uintptr_t)p) + 15) & ~(uintptr_t)15);
    p = srbf + (size_t)n_edges * NBF;
    float4* sgeo = (float4*)((((uintptr_t)p) + 15) & ~(uintptr_t)15);

    // weight-T offsets (ushort indices)
    const size_t O_MSG1 = 0, O_MSG2 = 196608, O_UV = 786432,
                 O_U1 = 1179648, O_U2 = 1572864, O_RO = 2162688;

    // ---- edge sort by recv + RBF precompute (layer-invariant) ----
    hipMemsetAsync(counts, 0, n_atoms * sizeof(int), stream);
    hist_kernel<<<(n_edges + 255) / 256, 256, 0, stream>>>(edge, counts, n_edges);
    scan_kernel<<<1, 256, 0, stream>>>(counts, startp, cursor, n_atoms);
    scatter_kernel<<<(n_edges + 255) / 256, 256, 0, stream>>>(
        edge, edge_diff, edge_dist, cursor, ssend, sgeo, srbf, n_edges);

    // ---- weights -> hi/lo bf16 transposed ----
    {
        dim3 wgrid(24, 16, 19);
        wconv_kernel<<<wgrid, 256, 0, stream>>>(
            (const float*)d_in[7], (const float*)d_in[9],
            (const float*)d_in[11], (const float*)d_in[13],
            (const float*)d_in[15], (const float*)d_in[17],
            (const float*)d_in[19], wTh, wTl);
        biascat_kernel<<<6, 256, 0, stream>>>(upd_bU, upd_bV, biasUV);
    }

    hipMemsetAsync(nvA, 0, (size_t)n_atoms * 768 * sizeof(float), stream);
    hipMemsetAsync(nv16A, 0, (size_t)n_atoms * 768 * sizeof(unsigned short), stream);
    init_ns_kernel<<<(n_atoms * 256 + 255) / 256, 256, 0, stream>>>(Z, embed, ns, n_atoms);

    float* nv_old = nvA;
    float* nv_new = nvB;
    unsigned short* nv16_old = nv16A;
    unsigned short* nv16_new = nv16B;

    for (int l = 0; l < 3; ++l) {
        // hid = silu(ns @ msg_w1 + b1)  [f32]
        launch_mgemm(1, 0, ns, wTh + O_MSG1 + (size_t)l * 65536,
                     wTl + O_MSG1 + (size_t)l * 65536, msg_b1 + l * 256,
                     hid, n_atoms, 256, 256, stream);
        // so16 = hid @ msg_w2 + b2  [bf16]
        launch_mgemm(0, 1, hid, wTh + O_MSG2 + (size_t)l * 196608,
                     wTl + O_MSG2 + (size_t)l * 196608, msg_b2 + l * 768,
                     so16, n_atoms, 768, 256, stream);

        agg_kernel<<<n_atoms, 256, 0, stream>>>(
            startp, ssend, sgeo, srbf,
            msg_w_filter + (size_t)l * NBF * 768, msg_b_filter + l * 768,
            so16, nv16_old, nv_old, ns, nv_new, nv16_new, n_atoms);

        // UV = nv_new(3M x 256) @ [wU|wV] + [bU|bV]  [f32]
        launch_mgemm(0, 0, nv_new, wTh + O_UV + (size_t)l * 131072,
                     wTl + O_UV + (size_t)l * 131072, biasUV + l * 512,
                     UV, n_atoms * 3, 512, 256, stream);

        vncat_kernel<<<(n_atoms * 256 + 255) / 256, 256, 0, stream>>>(UV, ns, s768, n_atoms);

        // hid = silu(cat @ upd_w1 + b1)  [f32], K=512
        launch_mgemm(1, 0, s768, wTh + O_U1 + (size_t)l * 131072,
                     wTl + O_U1 + (size_t)l * 131072, upd_b1 + l * 256,
                     hid, n_atoms, 256, 512, stream);
        // mlp = hid @ upd_w2 + b2  [f32] (overwrites s768)
        launch_mgemm(0, 0, hid, wTh + O_U2 + (size_t)l * 196608,
                     wTl + O_U2 + (size_t)l * 196608, upd_b2 + l * 768,
                     s768, n_atoms, 768, 256, stream);

        apply_update_kernel<<<(n_atoms * 256 + 255) / 256, 256, 0, stream>>>(
            s768, UV, nv_new, ns, nv16_new, n_atoms);

        { float* t = nv_old; nv_old = nv_new; nv_new = t; }
        { unsigned short* t = nv16_old; nv16_old = nv16_new; nv16_new = t; }
    }

    // readout
    launch_mgemm(1, 0, ns, wTh + O_RO, wTl + O_RO, ro_b1, hid, n_atoms, 256, 256, stream);
    readout_kernel<<<n_atoms, 64, 0, stream>>>(hid, ro_w2, ro_b2, out, n_atoms);
}

// Round 7
// 1008.935 us; speedup vs baseline: 3.1586x; 1.1814x over previous
//
#include <hip/hip_runtime.h>
#include <math.h>

#define FDIM 256
#define NBF 20
#define PI_F 3.14159265358979323846f
#define ECHUNK 64

typedef __attribute__((ext_vector_type(8))) short short8;
typedef __attribute__((ext_vector_type(4))) float f32x4;

__device__ __forceinline__ float silu_f(float x) {
    return x / (1.0f + __expf(-x));
}
__device__ __forceinline__ unsigned short f2bf(float f) {
    unsigned int x = __float_as_uint(f);
    unsigned int r = (x + 0x7fffu + ((x >> 16) & 1u)) >> 16;
    return (unsigned short)r;
}
__device__ __forceinline__ float bf2f(unsigned short u) {
    return __uint_as_float(((unsigned int)u) << 16);
}

// ---------------------------------------------------------------------------
// Split-bf16 MFMA GEMM (~fp32 accuracy): C = act(A_f32 @ B + bias)
// B pre-split transposed: Bh,Bl are (N,K) bf16; B ~= Bh + Bl.
// acc = Ah*Bh + Ah*Bl + Al*Bh
// BM=64, BN=128, BK=32, 256 thr (4 waves 2x2; wave tile 32x64 = 2x4 frags).
// Grid sized for M=5000: N=256 -> 158 blocks (vs 80 at BM=128).
// ---------------------------------------------------------------------------
template<int ACT, int OUTBF>
__global__ __launch_bounds__(256)
void mgemm_kernel(const float* __restrict__ A,
                  const unsigned short* __restrict__ Bh,
                  const unsigned short* __restrict__ Bl,
                  const float* __restrict__ bias,
                  void* __restrict__ Cout,
                  int M, int N, int K)
{
    __shared__ unsigned short As_hi[64][40];
    __shared__ unsigned short As_lo[64][40];
    __shared__ unsigned short Bs_hi[128][40];
    __shared__ unsigned short Bs_lo[128][40];

    const int bm = blockIdx.y * 64;
    const int bn = blockIdx.x * 128;
    const int tid = threadIdx.x;
    const int wid = tid >> 6;
    const int lane = tid & 63;
    const int wr = (wid >> 1) * 32;   // 0 / 32
    const int wc = (wid & 1) * 64;    // 0 / 64
    const int r16 = lane & 15;
    const int kg  = lane >> 4;

    f32x4 acc[2][4];
#pragma unroll
    for (int i = 0; i < 2; ++i)
#pragma unroll
        for (int j = 0; j < 4; ++j)
            acc[i][j] = (f32x4){0.f, 0.f, 0.f, 0.f};

    const int sra = tid >> 2;          // A stage row 0..63
    const int cba = (tid & 3) * 8;     // A stage col 0,8,16,24
    const int srb = tid >> 1;          // B stage row 0..127
    const int cbb = (tid & 1) * 16;    // B stage col 0/16

    for (int k0 = 0; k0 < K; k0 += 32) {
        __syncthreads();
        // ---- stage A (fp32 -> hi/lo bf16), one short8 per thread ----
        {
            const int gr = min(bm + sra, M - 1);
            const float* ap = &A[(size_t)gr * K + k0 + cba];
            short8 hv, lv;
#pragma unroll
            for (int q = 0; q < 2; ++q) {
                const float4 v = *(const float4*)(ap + q * 4);
                const float xs[4] = {v.x, v.y, v.z, v.w};
#pragma unroll
                for (int j = 0; j < 4; ++j) {
                    const int idx = q * 4 + j;
                    const unsigned short hh = f2bf(xs[j]);
                    hv[idx] = (short)hh;
                    lv[idx] = (short)f2bf(xs[j] - bf2f(hh));
                }
            }
            *(short8*)&As_hi[sra][cba] = hv;
            *(short8*)&As_lo[sra][cba] = lv;
        }
        // ---- stage B (pre-split bf16), two short8 per thread ----
        {
            const size_t bo = (size_t)(bn + srb) * K + k0 + cbb;
            *(short8*)&Bs_hi[srb][cbb]     = *(const short8*)&Bh[bo];
            *(short8*)&Bs_hi[srb][cbb + 8] = *(const short8*)&Bh[bo + 8];
            *(short8*)&Bs_lo[srb][cbb]     = *(const short8*)&Bl[bo];
            *(short8*)&Bs_lo[srb][cbb + 8] = *(const short8*)&Bl[bo + 8];
        }
        __syncthreads();

        short8 ah[2], al[2], bh4[4], bl4[4];
#pragma unroll
        for (int fr = 0; fr < 2; ++fr) {
            ah[fr] = *(const short8*)&As_hi[wr + fr * 16 + r16][kg * 8];
            al[fr] = *(const short8*)&As_lo[wr + fr * 16 + r16][kg * 8];
        }
#pragma unroll
        for (int fc = 0; fc < 4; ++fc) {
            bh4[fc] = *(const short8*)&Bs_hi[wc + fc * 16 + r16][kg * 8];
            bl4[fc] = *(const short8*)&Bs_lo[wc + fc * 16 + r16][kg * 8];
        }
#pragma unroll
        for (int fr = 0; fr < 2; ++fr)
#pragma unroll
            for (int fc = 0; fc < 4; ++fc) {
                acc[fr][fc] = __builtin_amdgcn_mfma_f32_16x16x32_bf16(
                    al[fr], bh4[fc], acc[fr][fc], 0, 0, 0);
                acc[fr][fc] = __builtin_amdgcn_mfma_f32_16x16x32_bf16(
                    ah[fr], bl4[fc], acc[fr][fc], 0, 0, 0);
                acc[fr][fc] = __builtin_amdgcn_mfma_f32_16x16x32_bf16(
                    ah[fr], bh4[fc], acc[fr][fc], 0, 0, 0);
            }
    }

    // epilogue: C/D layout col=lane&15, row=(lane>>4)*4+reg
#pragma unroll
    for (int fr = 0; fr < 2; ++fr) {
#pragma unroll
        for (int fc = 0; fc < 4; ++fc) {
            const int col = bn + wc + fc * 16 + r16;
            const int row0 = bm + wr + fr * 16 + kg * 4;
            const float bsc = bias[col];
            const f32x4 v = acc[fr][fc];
#pragma unroll
            for (int j = 0; j < 4; ++j) {
                const int row = row0 + j;
                if (row < M) {
                    float x = v[j] + bsc;
                    if (ACT) x = silu_f(x);
                    if (OUTBF)
                        ((unsigned short*)Cout)[(size_t)row * N + col] = f2bf(x);
                    else
                        ((float*)Cout)[(size_t)row * N + col] = x;
                }
            }
        }
    }
}

// ---------------------------------------------------------------------------
// Weight transpose + hi/lo bf16 split. blockIdx.z = weight id (0..18).
// ---------------------------------------------------------------------------
__global__ __launch_bounds__(256)
void wconv_kernel(const float* __restrict__ msg_w1, const float* __restrict__ msg_w2,
                  const float* __restrict__ upd_wU, const float* __restrict__ upd_wV,
                  const float* __restrict__ upd_w1, const float* __restrict__ upd_w2,
                  const float* __restrict__ ro_w1,
                  unsigned short* __restrict__ wTh, unsigned short* __restrict__ wTl)
{
    const int id = blockIdx.z;
    const float* src; int R, C; size_t doff;
    if (id < 18) {
        const int l = id / 6, w = id % 6;
        switch (w) {
        case 0: src = msg_w1 + (size_t)l * 65536;  R = 256; C = 256; doff = 0       + (size_t)l * 65536;  break;
        case 1: src = msg_w2 + (size_t)l * 196608; R = 256; C = 768; doff = 196608  + (size_t)l * 196608; break;
        case 2: src = upd_wU + (size_t)l * 65536;  R = 256; C = 256; doff = 786432  + (size_t)l * 131072; break;
        case 3: src = upd_wV + (size_t)l * 65536;  R = 256; C = 256; doff = 786432  + (size_t)l * 131072 + 65536; break;
        case 4: src = upd_w1 + (size_t)l * 131072; R = 512; C = 256; doff = 1179648 + (size_t)l * 131072; break;
        default: src = upd_w2 + (size_t)l * 196608; R = 256; C = 768; doff = 1572864 + (size_t)l * 196608; break;
        }
    } else { src = ro_w1; R = 256; C = 256; doff = 2162688; }

    if (blockIdx.x * 32 >= C || blockIdx.y * 32 >= R) return;

    __shared__ float t[32][33];
    const int x = threadIdx.x & 31, y4 = threadIdx.x >> 5;
    for (int yy = y4; yy < 32; yy += 8) {
        const int r = blockIdx.y * 32 + yy, c = blockIdx.x * 32 + x;
        t[yy][x] = (r < R && c < C) ? src[(size_t)r * C + c] : 0.f;
    }
    __syncthreads();
    for (int yy = y4; yy < 32; yy += 8) {
        const int c = blockIdx.x * 32 + yy, r = blockIdx.y * 32 + x;
        if (c < C && r < R) {
            const float v = t[x][yy];
            const unsigned short h = f2bf(v);
            wTh[doff + (size_t)c * R + r] = h;
            wTl[doff + (size_t)c * R + r] = f2bf(v - bf2f(h));
        }
    }
}

// biasUV[l][0:256]=upd_bU[l], [256:512]=upd_bV[l]
__global__ void biascat_kernel(const float* __restrict__ bU,
                               const float* __restrict__ bV,
                               float* __restrict__ o)
{
    int i = blockIdx.x * 256 + threadIdx.x;
    if (i >= 1536) return;
    int l = i >> 9, j = i & 511;
    o[i] = (j < 256) ? bU[l * 256 + j] : bV[l * 256 + j - 256];
}

// ---------------------------------------------------------------------------
__global__ void init_ns_kernel(const int* __restrict__ Z,
                               const float* __restrict__ embed,
                               float* __restrict__ ns, int n_atoms)
{
    int i = blockIdx.x * 256 + threadIdx.x;
    if (i >= n_atoms * FDIM) return;
    int a = i >> 8, f = i & 255;
    ns[i] = embed[Z[a] * FDIM + f];
}

// ---------------------------------------------------------------------------
// Counting sort of edges by recv atom.
// ---------------------------------------------------------------------------
__global__ void hist_kernel(const int* __restrict__ edge, int* __restrict__ counts,
                            int n_edges)
{
    int e = blockIdx.x * 256 + threadIdx.x;
    if (e >= n_edges) return;
    atomicAdd(&counts[edge[2 * e]], 1);
}

__global__ __launch_bounds__(256)
void scan_kernel(const int* __restrict__ counts, int* __restrict__ start,
                 int* __restrict__ cursor, int n)
{
    __shared__ int sums[256];
    const int t = threadIdx.x;
    const int base = t * 20;
    int local[20];
    int s = 0;
#pragma unroll
    for (int i = 0; i < 20; ++i) {
        int c = (base + i < n) ? counts[base + i] : 0;
        local[i] = s;
        s += c;
    }
    sums[t] = s;
    __syncthreads();
    for (int off = 1; off < 256; off <<= 1) {
        int v = (t >= off) ? sums[t - off] : 0;
        __syncthreads();
        sums[t] += v;
        __syncthreads();
    }
    const int pre = (t > 0) ? sums[t - 1] : 0;
#pragma unroll
    for (int i = 0; i < 20; ++i) {
        if (base + i < n) {
            start[base + i] = pre + local[i];
            cursor[base + i] = pre + local[i];
        }
    }
    if (t == 255) start[n] = sums[255];
}

__global__ void scatter_kernel(const int* __restrict__ edge,
                               const float* __restrict__ edge_diff,
                               const float* __restrict__ edge_dist,
                               int* __restrict__ cursor,
                               int* __restrict__ ssend,
                               float4* __restrict__ sgeo,
                               float* __restrict__ srbf,
                               int n_edges)
{
    int e = blockIdx.x * 256 + threadIdx.x;
    if (e >= n_edges) return;
    const int recv = edge[2 * e + 0];
    const int send = edge[2 * e + 1];
    const int pos = atomicAdd(&cursor[recv], 1);
    const float dist = edge_dist[e];
    const float inv = 1.0f / dist;
    const float fcut = (dist < 5.0f)
        ? 0.5f * (__cosf(dist * (PI_F / 5.0f)) + 1.0f) : 0.0f;
    float4 g;
    g.x = edge_diff[3 * e + 0] * inv;
    g.y = edge_diff[3 * e + 1] * inv;
    g.z = edge_diff[3 * e + 2] * inv;
    g.w = fcut;
    ssend[pos] = send;
    sgeo[pos] = g;
    float* rp = srbf + (size_t)pos * NBF;
    const float sc = fcut * inv;
#pragma unroll
    for (int k = 0; k < NBF; ++k)
        rp[k] = __sinf(dist * ((k + 1) * (PI_F / 5.0f))) * sc;
}

// ---------------------------------------------------------------------------
// Per-atom message aggregation. One block (256 thr) per atom.
// Edge metadata (srbf/sgeo/ssend) LDS-staged in 64-edge chunks:
// uniform VMEM reads -> broadcast ds_reads (lgkm), frees vmcnt for gathers.
// ---------------------------------------------------------------------------
__global__ __launch_bounds__(256, 2)
void agg_kernel(const int* __restrict__ start,
                const int* __restrict__ ssend,
                const float4* __restrict__ sgeo,
                const float* __restrict__ srbf,
                const float* __restrict__ wf,    // (20,768) this layer
                const float* __restrict__ bf,    // (768)
                const unsigned short* __restrict__ so16,  // (n_atoms,768) bf16
                const unsigned short* __restrict__ nv16,  // (n_atoms,768) bf16
                const float* __restrict__ nv_old,// (n_atoms,3,256) fp32
                float* __restrict__ ns,          // += msg_s
                float* __restrict__ nv_new,      // = nv_old + sum(msg_v)
                unsigned short* __restrict__ nv16n, // bf16 copy of nv_new
                int n_atoms)
{
    __shared__ float  s_rbf[ECHUNK * NBF];   // 5120 B
    __shared__ float4 s_geo[ECHUNK];         // 1024 B
    __shared__ int    s_send[ECHUNK];        //  256 B

    const int f = threadIdx.x;
    const int a = blockIdx.x;
    float w0[NBF], w1[NBF], w2[NBF];
#pragma unroll
    for (int k = 0; k < NBF; ++k) {
        w0[k] = wf[k * 768 + f];
        w1[k] = wf[k * 768 + 256 + f];
        w2[k] = wf[k * 768 + 512 + f];
    }
    const float b0 = bf[f], b1 = bf[256 + f], b2 = bf[512 + f];

    float accs = 0.0f, av0 = 0.0f, av1 = 0.0f, av2 = 0.0f;
    const int i0 = start[a], i1 = start[a + 1];

    for (int c0 = i0; c0 < i1; c0 += ECHUNK) {
        const int cnt = min(ECHUNK, i1 - c0);
        __syncthreads();
        // stage srbf (contiguous, 80B/edge -> 16B aligned float4 copies)
        {
            const float4* src = (const float4*)(srbf + (size_t)c0 * NBF);
            for (int t = f; t < cnt * (NBF / 4); t += 256)
                ((float4*)s_rbf)[t] = src[t];
            for (int t = f; t < cnt; t += 256) {
                s_geo[t] = sgeo[c0 + t];
                s_send[t] = ssend[c0 + t];
            }
        }
        __syncthreads();

        for (int e = 0; e < cnt; ++e) {
            const int send = s_send[e];
            const float4 g = s_geo[e];
            float f0 = g.w * b0, f1 = g.w * b1, f2 = g.w * b2;
#pragma unroll
            for (int k = 0; k < NBF; ++k) {
                const float r = s_rbf[e * NBF + k];
                f0 = fmaf(r, w0[k], f0);
                f1 = fmaf(r, w1[k], f1);
                f2 = fmaf(r, w2[k], f2);
            }

            const unsigned short* sp = so16 + (size_t)send * 768;
            const float gv = f0 * bf2f(sp[f]);
            const float ge = f1 * bf2f(sp[256 + f]);
            const float ms = f2 * bf2f(sp[512 + f]);
            accs += ms;

            const unsigned short* nvp = nv16 + (size_t)send * 768;
            av0 += fmaf(bf2f(nvp[f]),       gv, g.x * ge);
            av1 += fmaf(bf2f(nvp[256 + f]), gv, g.y * ge);
            av2 += fmaf(bf2f(nvp[512 + f]), gv, g.z * ge);
        }
    }

    ns[(size_t)a * 256 + f] += accs;
    const size_t b = (size_t)a * 768 + f;
    float nvv;
    nvv = nv_old[b]       + av0; nv_new[b]       = nvv; nv16n[b]       = f2bf(nvv);
    nvv = nv_old[b + 256] + av1; nv_new[b + 256] = nvv; nv16n[b + 256] = f2bf(nvv);
    nvv = nv_old[b + 512] + av2; nv_new[b + 512] = nvv; nv16n[b + 512] = f2bf(nvv);
}

// ---------------------------------------------------------------------------
// cat[a][0:256] = |Vv[a,:,f]| ; cat[a][256:512] = ns[a][f]
// UV layout: row (a*3+d) of 512; Uv = [0:256], Vv = [256:512]
// ---------------------------------------------------------------------------
__global__ void vncat_kernel(const float* __restrict__ UV,
                             const float* __restrict__ ns,
                             float* __restrict__ cat, int n_atoms)
{
    int i = blockIdx.x * 256 + threadIdx.x;
    if (i >= n_atoms * FDIM) return;
    int a = i >> 8, f = i & 255;
    const float v0 = UV[((size_t)a * 3 + 0) * 512 + 256 + f];
    const float v1 = UV[((size_t)a * 3 + 1) * 512 + 256 + f];
    const float v2 = UV[((size_t)a * 3 + 2) * 512 + 256 + f];
    cat[(size_t)a * 512 + f] = sqrtf(v0 * v0 + v1 * v1 + v2 * v2);
    cat[(size_t)a * 512 + 256 + f] = ns[(size_t)a * 256 + f];
}

// ---------------------------------------------------------------------------
__global__ void apply_update_kernel(const float* __restrict__ mlp,
                                    const float* __restrict__ UV,
                                    float* __restrict__ nv,
                                    float* __restrict__ ns,
                                    unsigned short* __restrict__ nv16,
                                    int n_atoms)
{
    int i = blockIdx.x * 256 + threadIdx.x;
    if (i >= n_atoms * FDIM) return;
    int a = i >> 8, f = i & 255;
    const float avv = mlp[(size_t)a * 768 + f];
    const float asv = mlp[(size_t)a * 768 + 256 + f];
    const float ass = mlp[(size_t)a * 768 + 512 + f];
    float dot = 0.0f;
#pragma unroll
    for (int d = 0; d < 3; ++d) {
        const size_t iuv = ((size_t)a * 3 + d) * 512 + f;
        const float u = UV[iuv];
        const float v = UV[iuv + 256];
        const size_t inv_ = (size_t)a * 768 + d * 256 + f;
        const float nn = fmaf(avv, u, nv[inv_]);
        nv[inv_] = nn;
        nv16[inv_] = f2bf(nn);
        dot = fmaf(u, v, dot);
    }
    const float nsv = ns[i] + fmaf(asv, dot, ass);
    ns[i] = nsv;
}

// ---------------------------------------------------------------------------
__global__ void readout_kernel(const float* __restrict__ hid,
                               const float* __restrict__ w2,
                               const float* __restrict__ b2,
                               float* __restrict__ out, int n_atoms)
{
    const int a = blockIdx.x;
    const int lane = threadIdx.x; // 64
    const float* h = hid + (size_t)a * FDIM;
    float s = 0.0f;
#pragma unroll
    for (int i = 0; i < 4; ++i)
        s += h[lane + 64 * i] * w2[lane + 64 * i];
#pragma unroll
    for (int off = 32; off > 0; off >>= 1)
        s += __shfl_down(s, off);
    if (lane == 0) out[a] = s + b2[0];
}

// ---------------------------------------------------------------------------
static inline void launch_mgemm(int act, int obf, const float* A,
                                const unsigned short* Bh, const unsigned short* Bl,
                                const float* bias, void* C,
                                int M, int N, int K, hipStream_t s)
{
    dim3 grid(N / 128, (M + 63) / 64);
    if (act) {
        if (obf) mgemm_kernel<1, 1><<<grid, 256, 0, s>>>(A, Bh, Bl, bias, C, M, N, K);
        else     mgemm_kernel<1, 0><<<grid, 256, 0, s>>>(A, Bh, Bl, bias, C, M, N, K);
    } else {
        if (obf) mgemm_kernel<0, 1><<<grid, 256, 0, s>>>(A, Bh, Bl, bias, C, M, N, K);
        else     mgemm_kernel<0, 0><<<grid, 256, 0, s>>>(A, Bh, Bl, bias, C, M, N, K);
    }
}

extern "C" void kernel_launch(void* const* d_in, const int* in_sizes, int n_in,
                              void* d_out, int out_size, void* d_ws, size_t ws_size,
                              hipStream_t stream)
{
    const int*   Z            = (const int*)  d_in[0];
    const int*   edge         = (const int*)  d_in[1];
    const float* edge_diff    = (const float*)d_in[2];
    const float* edge_dist    = (const float*)d_in[3];
    const float* embed        = (const float*)d_in[4];
    const float* msg_w_filter = (const float*)d_in[5];
    const float* msg_b_filter = (const float*)d_in[6];
    const float* msg_b1       = (const float*)d_in[8];
    const float* msg_b2       = (const float*)d_in[10];
    const float* upd_bU       = (const float*)d_in[12];
    const float* upd_bV       = (const float*)d_in[14];
    const float* upd_b1       = (const float*)d_in[16];
    const float* upd_b2       = (const float*)d_in[18];
    const float* ro_b1        = (const float*)d_in[20];
    const float* ro_w2        = (const float*)d_in[21];
    const float* ro_b2        = (const float*)d_in[22];
    float* out = (float*)d_out;

    const int n_atoms = in_sizes[0];
    const int n_edges = in_sizes[1] / 2;

    // ---- workspace layout ----
    float* p   = (float*)d_ws;
    float* ns   = p; p += (size_t)n_atoms * 256;
    float* nvA  = p; p += (size_t)n_atoms * 768;
    float* nvB  = p; p += (size_t)n_atoms * 768;
    float* s768 = p; p += (size_t)n_atoms * 768;   // cat (as Mx512) then mlp (Mx768)
    float* UV   = p; p += (size_t)n_atoms * 1536;  // fused U|V, rows = 3*n_atoms
    float* hid  = p; p += (size_t)n_atoms * 256;
    unsigned short* so16  = (unsigned short*)p;  p = (float*)(so16  + (size_t)n_atoms * 768);
    unsigned short* nv16A = (unsigned short*)p;  p = (float*)(nv16A + (size_t)n_atoms * 768);
    unsigned short* nv16B = (unsigned short*)p;  p = (float*)(nv16B + (size_t)n_atoms * 768);
    unsigned short* wTh   = (unsigned short*)p;  p = (float*)(wTh + 2228224);
    unsigned short* wTl   = (unsigned short*)p;  p = (float*)(wTl + 2228224);
    float* biasUV = p; p += 1536;
    int*   counts = (int*)p;   p += n_atoms;
    int*   cursor = (int*)p;   p += n_atoms;
    int*   startp = (int*)p;   p += n_atoms + 4;
    int*   ssend  = (int*)p;   p += n_edges;
    float* srbf = (float*)((((uintptr_t)p) + 15) & ~(uintptr_t)15);
    p = srbf + (size_t)n_edges * NBF;
    float4* sgeo = (float4*)((((uintptr_t)p) + 15) & ~(uintptr_t)15);

    // weight-T offsets (ushort indices)
    const size_t O_MSG1 = 0, O_MSG2 = 196608, O_UV = 786432,
                 O_U1 = 1179648, O_U2 = 1572864, O_RO = 2162688;

    // ---- edge sort by recv + RBF precompute (layer-invariant) ----
    hipMemsetAsync(counts, 0, n_atoms * sizeof(int), stream);
    hist_kernel<<<(n_edges + 255) / 256, 256, 0, stream>>>(edge, counts, n_edges);
    scan_kernel<<<1, 256, 0, stream>>>(counts, startp, cursor, n_atoms);
    scatter_kernel<<<(n_edges + 255) / 256, 256, 0, stream>>>(
        edge, edge_diff, edge_dist, cursor, ssend, sgeo, srbf, n_edges);

    // ---- weights -> hi/lo bf16 transposed ----
    {
        dim3 wgrid(24, 16, 19);
        wconv_kernel<<<wgrid, 256, 0, stream>>>(
            (const float*)d_in[7], (const float*)d_in[9],
            (const float*)d_in[11], (const float*)d_in[13],
            (const float*)d_in[15], (const float*)d_in[17],
            (const float*)d_in[19], wTh, wTl);
        biascat_kernel<<<6, 256, 0, stream>>>(upd_bU, upd_bV, biasUV);
    }

    hipMemsetAsync(nvA, 0, (size_t)n_atoms * 768 * sizeof(float), stream);
    hipMemsetAsync(nv16A, 0, (size_t)n_atoms * 768 * sizeof(unsigned short), stream);
    init_ns_kernel<<<(n_atoms * 256 + 255) / 256, 256, 0, stream>>>(Z, embed, ns, n_atoms);

    float* nv_old = nvA;
    float* nv_new = nvB;
    unsigned short* nv16_old = nv16A;
    unsigned short* nv16_new = nv16B;

    for (int l = 0; l < 3; ++l) {
        // hid = silu(ns @ msg_w1 + b1)  [f32]
        launch_mgemm(1, 0, ns, wTh + O_MSG1 + (size_t)l * 65536,
                     wTl + O_MSG1 + (size_t)l * 65536, msg_b1 + l * 256,
                     hid, n_atoms, 256, 256, stream);
        // so16 = hid @ msg_w2 + b2  [bf16]
        launch_mgemm(0, 1, hid, wTh + O_MSG2 + (size_t)l * 196608,
                     wTl + O_MSG2 + (size_t)l * 196608, msg_b2 + l * 768,
                     so16, n_atoms, 768, 256, stream);

        agg_kernel<<<n_atoms, 256, 0, stream>>>(
            startp, ssend, sgeo, srbf,
            msg_w_filter + (size_t)l * NBF * 768, msg_b_filter + l * 768,
            so16, nv16_old, nv_old, ns, nv_new, nv16_new, n_atoms);

        // UV = nv_new(3M x 256) @ [wU|wV] + [bU|bV]  [f32]
        launch_mgemm(0, 0, nv_new, wTh + O_UV + (size_t)l * 131072,
                     wTl + O_UV + (size_t)l * 131072, biasUV + l * 512,
                     UV, n_atoms * 3, 512, 256, stream);

        vncat_kernel<<<(n_atoms * 256 + 255) / 256, 256, 0, stream>>>(UV, ns, s768, n_atoms);

        // hid = silu(cat @ upd_w1 + b1)  [f32], K=512
        launch_mgemm(1, 0, s768, wTh + O_U1 + (size_t)l * 131072,
                     wTl + O_U1 + (size_t)l * 131072, upd_b1 + l * 256,
                     hid, n_atoms, 256, 512, stream);
        // mlp = hid @ upd_w2 + b2  [f32] (overwrites s768)
        launch_mgemm(0, 0, hid, wTh + O_U2 + (size_t)l * 196608,
                     wTl + O_U2 + (size_t)l * 196608, upd_b2 + l * 768,
                     s768, n_atoms, 768, 256, stream);

        apply_update_kernel<<<(n_atoms * 256 + 255) / 256, 256, 0, stream>>>(
            s768, UV, nv_new, ns, nv16_new, n_atoms);

        { float* t = nv_old; nv_old = nv_new; nv_new = t; }
        { unsigned short* t = nv16_old; nv16_old = nv16_new; nv16_new = t; }
    }

    // readout
    launch_mgemm(1, 0, ns, wTh + O_RO, wTl + O_RO, ro_b1, hid, n_atoms, 256, 256, stream);
    readout_kernel<<<n_atoms, 64, 0, stream>>>(hid, ro_w2, ro_b2, out, n_atoms);
}

// Round 11
// 929.126 us; speedup vs baseline: 3.4299x; 1.0859x over previous
//
#include <hip/hip_runtime.h>
#include <math.h>

#define FDIM 256
#define NBF 20
#define PI_F 3.14159265358979323846f
#define ECHUNK 64

typedef __attribute__((ext_vector_type(8))) short short8;
typedef __attribute__((ext_vector_type(4))) float f32x4;
typedef __fp16 half2_t __attribute__((ext_vector_type(2)));

__device__ __forceinline__ float silu_f(float x) {
    return x / (1.0f + __expf(-x));
}
__device__ __forceinline__ unsigned short f2bf(float f) {
    unsigned int x = __float_as_uint(f);
    unsigned int r = (x + 0x7fffu + ((x >> 16) & 1u)) >> 16;
    return (unsigned short)r;
}
__device__ __forceinline__ float bf2f(unsigned short u) {
    return __uint_as_float(((unsigned int)u) << 16);
}
__device__ __forceinline__ unsigned int h2u(half2_t h) {
    return __builtin_bit_cast(unsigned int, h);
}
__device__ __forceinline__ half2_t u2h(unsigned int u) {
    return __builtin_bit_cast(half2_t, u);
}
// round-to-nearest-even f16 pack (NOT cvt_pkrtz, which is RTZ and biased)
__device__ __forceinline__ half2_t pk_rne(float a, float b) {
    half2_t h;
    h[0] = (__fp16)a;   // v_cvt_f16_f32 (RNE)
    h[1] = (__fp16)b;
    return h;
}

// ---------------------------------------------------------------------------
// Split-bf16 MFMA GEMM (~fp32 accuracy): C = act(A_f32 @ B + bias)
// B pre-split transposed: Bh,Bl are (N,K) bf16; B ~= Bh + Bl.
// acc = Ah*Bh + Ah*Bl + Al*Bh
// BM=64, BN=128, BK=32, 256 thr (4 waves 2x2; wave tile 32x64 = 2x4 frags).
// ---------------------------------------------------------------------------
template<int ACT, int OUTBF>
__global__ __launch_bounds__(256)
void mgemm_kernel(const float* __restrict__ A,
                  const unsigned short* __restrict__ Bh,
                  const unsigned short* __restrict__ Bl,
                  const float* __restrict__ bias,
                  void* __restrict__ Cout,
                  int M, int N, int K)
{
    __shared__ unsigned short As_hi[64][40];
    __shared__ unsigned short As_lo[64][40];
    __shared__ unsigned short Bs_hi[128][40];
    __shared__ unsigned short Bs_lo[128][40];

    const int bm = blockIdx.y * 64;
    const int bn = blockIdx.x * 128;
    const int tid = threadIdx.x;
    const int wid = tid >> 6;
    const int lane = tid & 63;
    const int wr = (wid >> 1) * 32;   // 0 / 32
    const int wc = (wid & 1) * 64;    // 0 / 64
    const int r16 = lane & 15;
    const int kg  = lane >> 4;

    f32x4 acc[2][4];
#pragma unroll
    for (int i = 0; i < 2; ++i)
#pragma unroll
        for (int j = 0; j < 4; ++j)
            acc[i][j] = (f32x4){0.f, 0.f, 0.f, 0.f};

    const int sra = tid >> 2;          // A stage row 0..63
    const int cba = (tid & 3) * 8;     // A stage col 0,8,16,24
    const int srb = tid >> 1;          // B stage row 0..127
    const int cbb = (tid & 1) * 16;    // B stage col 0/16

    for (int k0 = 0; k0 < K; k0 += 32) {
        __syncthreads();
        // ---- stage A (fp32 -> hi/lo bf16), one short8 per thread ----
        {
            const int gr = min(bm + sra, M - 1);
            const float* ap = &A[(size_t)gr * K + k0 + cba];
            short8 hv, lv;
#pragma unroll
            for (int q = 0; q < 2; ++q) {
                const float4 v = *(const float4*)(ap + q * 4);
                const float xs[4] = {v.x, v.y, v.z, v.w};
#pragma unroll
                for (int j = 0; j < 4; ++j) {
                    const int idx = q * 4 + j;
                    const unsigned short hh = f2bf(xs[j]);
                    hv[idx] = (short)hh;
                    lv[idx] = (short)f2bf(xs[j] - bf2f(hh));
                }
            }
            *(short8*)&As_hi[sra][cba] = hv;
            *(short8*)&As_lo[sra][cba] = lv;
        }
        // ---- stage B (pre-split bf16), two short8 per thread ----
        {
            const size_t bo = (size_t)(bn + srb) * K + k0 + cbb;
            *(short8*)&Bs_hi[srb][cbb]     = *(const short8*)&Bh[bo];
            *(short8*)&Bs_hi[srb][cbb + 8] = *(const short8*)&Bh[bo + 8];
            *(short8*)&Bs_lo[srb][cbb]     = *(const short8*)&Bl[bo];
            *(short8*)&Bs_lo[srb][cbb + 8] = *(const short8*)&Bl[bo + 8];
        }
        __syncthreads();

        short8 ah[2], al[2], bh4[4], bl4[4];
#pragma unroll
        for (int fr = 0; fr < 2; ++fr) {
            ah[fr] = *(const short8*)&As_hi[wr + fr * 16 + r16][kg * 8];
            al[fr] = *(const short8*)&As_lo[wr + fr * 16 + r16][kg * 8];
        }
#pragma unroll
        for (int fc = 0; fc < 4; ++fc) {
            bh4[fc] = *(const short8*)&Bs_hi[wc + fc * 16 + r16][kg * 8];
            bl4[fc] = *(const short8*)&Bs_lo[wc + fc * 16 + r16][kg * 8];
        }
#pragma unroll
        for (int fr = 0; fr < 2; ++fr)
#pragma unroll
            for (int fc = 0; fc < 4; ++fc) {
                acc[fr][fc] = __builtin_amdgcn_mfma_f32_16x16x32_bf16(
                    al[fr], bh4[fc], acc[fr][fc], 0, 0, 0);
                acc[fr][fc] = __builtin_amdgcn_mfma_f32_16x16x32_bf16(
                    ah[fr], bl4[fc], acc[fr][fc], 0, 0, 0);
                acc[fr][fc] = __builtin_amdgcn_mfma_f32_16x16x32_bf16(
                    ah[fr], bh4[fc], acc[fr][fc], 0, 0, 0);
            }
    }

    // epilogue: C/D layout col=lane&15, row=(lane>>4)*4+reg
#pragma unroll
    for (int fr = 0; fr < 2; ++fr) {
#pragma unroll
        for (int fc = 0; fc < 4; ++fc) {
            const int col = bn + wc + fc * 16 + r16;
            const int row0 = bm + wr + fr * 16 + kg * 4;
            const float bsc = bias[col];
            const f32x4 v = acc[fr][fc];
#pragma unroll
            for (int j = 0; j < 4; ++j) {
                const int row = row0 + j;
                if (row < M) {
                    float x = v[j] + bsc;
                    if (ACT) x = silu_f(x);
                    if (OUTBF)
                        ((unsigned short*)Cout)[(size_t)row * N + col] = f2bf(x);
                    else
                        ((float*)Cout)[(size_t)row * N + col] = x;
                }
            }
        }
    }
}

// ---------------------------------------------------------------------------
// Weight transpose + hi/lo bf16 split. blockIdx.z = weight id (0..18).
// ---------------------------------------------------------------------------
__global__ __launch_bounds__(256)
void wconv_kernel(const float* __restrict__ msg_w1, const float* __restrict__ msg_w2,
                  const float* __restrict__ upd_wU, const float* __restrict__ upd_wV,
                  const float* __restrict__ upd_w1, const float* __restrict__ upd_w2,
                  const float* __restrict__ ro_w1,
                  unsigned short* __restrict__ wTh, unsigned short* __restrict__ wTl)
{
    const int id = blockIdx.z;
    const float* src; int R, C; size_t doff;
    if (id < 18) {
        const int l = id / 6, w = id % 6;
        switch (w) {
        case 0: src = msg_w1 + (size_t)l * 65536;  R = 256; C = 256; doff = 0       + (size_t)l * 65536;  break;
        case 1: src = msg_w2 + (size_t)l * 196608; R = 256; C = 768; doff = 196608  + (size_t)l * 196608; break;
        case 2: src = upd_wU + (size_t)l * 65536;  R = 256; C = 256; doff = 786432  + (size_t)l * 131072; break;
        case 3: src = upd_wV + (size_t)l * 65536;  R = 256; C = 256; doff = 786432  + (size_t)l * 131072 + 65536; break;
        case 4: src = upd_w1 + (size_t)l * 131072; R = 512; C = 256; doff = 1179648 + (size_t)l * 131072; break;
        default: src = upd_w2 + (size_t)l * 196608; R = 256; C = 768; doff = 1572864 + (size_t)l * 196608; break;
        }
    } else { src = ro_w1; R = 256; C = 256; doff = 2162688; }

    if (blockIdx.x * 32 >= C || blockIdx.y * 32 >= R) return;

    __shared__ float t[32][33];
    const int x = threadIdx.x & 31, y4 = threadIdx.x >> 5;
    for (int yy = y4; yy < 32; yy += 8) {
        const int r = blockIdx.y * 32 + yy, c = blockIdx.x * 32 + x;
        t[yy][x] = (r < R && c < C) ? src[(size_t)r * C + c] : 0.f;
    }
    __syncthreads();
    for (int yy = y4; yy < 32; yy += 8) {
        const int c = blockIdx.x * 32 + yy, r = blockIdx.y * 32 + x;
        if (c < C && r < R) {
            const float v = t[x][yy];
            const unsigned short h = f2bf(v);
            wTh[doff + (size_t)c * R + r] = h;
            wTl[doff + (size_t)c * R + r] = f2bf(v - bf2f(h));
        }
    }
}

// biasUV[l][0:256]=upd_bU[l], [256:512]=upd_bV[l]
__global__ void biascat_kernel(const float* __restrict__ bU,
                               const float* __restrict__ bV,
                               float* __restrict__ o)
{
    int i = blockIdx.x * 256 + threadIdx.x;
    if (i >= 1536) return;
    int l = i >> 9, j = i & 511;
    o[i] = (j < 256) ? bU[l * 256 + j] : bV[l * 256 + j - 256];
}

// ---------------------------------------------------------------------------
__global__ void init_ns_kernel(const int* __restrict__ Z,
                               const float* __restrict__ embed,
                               float* __restrict__ ns, int n_atoms)
{
    int i = blockIdx.x * 256 + threadIdx.x;
    if (i >= n_atoms * FDIM) return;
    int a = i >> 8, f = i & 255;
    ns[i] = embed[Z[a] * FDIM + f];
}

// ---------------------------------------------------------------------------
// Counting sort of edges by recv atom.
// ---------------------------------------------------------------------------
__global__ void hist_kernel(const int* __restrict__ edge, int* __restrict__ counts,
                            int n_edges)
{
    int e = blockIdx.x * 256 + threadIdx.x;
    if (e >= n_edges) return;
    atomicAdd(&counts[edge[2 * e]], 1);
}

__global__ __launch_bounds__(256)
void scan_kernel(const int* __restrict__ counts, int* __restrict__ start,
                 int* __restrict__ cursor, int n)
{
    __shared__ int sums[256];
    const int t = threadIdx.x;
    const int base = t * 20;
    int local[20];
    int s = 0;
#pragma unroll
    for (int i = 0; i < 20; ++i) {
        int c = (base + i < n) ? counts[base + i] : 0;
        local[i] = s;
        s += c;
    }
    sums[t] = s;
    __syncthreads();
    for (int off = 1; off < 256; off <<= 1) {
        int v = (t >= off) ? sums[t - off] : 0;
        __syncthreads();
        sums[t] += v;
        __syncthreads();
    }
    const int pre = (t > 0) ? sums[t - 1] : 0;
#pragma unroll
    for (int i = 0; i < 20; ++i) {
        if (base + i < n) {
            start[base + i] = pre + local[i];
            cursor[base + i] = pre + local[i];
        }
    }
    if (t == 255) start[n] = sums[255];
}

// Scatter into recv-sorted order; RBF precomputed as packed f16 pairs
// (10 dwords/edge, RNE-rounded) for v_dot2_f32_f16 consumption in agg.
__global__ void scatter_kernel(const int* __restrict__ edge,
                               const float* __restrict__ edge_diff,
                               const float* __restrict__ edge_dist,
                               int* __restrict__ cursor,
                               int* __restrict__ ssend,
                               float4* __restrict__ sgeo,
                               unsigned int* __restrict__ srbf,
                               int n_edges)
{
    int e = blockIdx.x * 256 + threadIdx.x;
    if (e >= n_edges) return;
    const int recv = edge[2 * e + 0];
    const int send = edge[2 * e + 1];
    const int pos = atomicAdd(&cursor[recv], 1);
    const float dist = edge_dist[e];
    const float inv = 1.0f / dist;
    const float fcut = (dist < 5.0f)
        ? 0.5f * (__cosf(dist * (PI_F / 5.0f)) + 1.0f) : 0.0f;
    float4 g;
    g.x = edge_diff[3 * e + 0] * inv;
    g.y = edge_diff[3 * e + 1] * inv;
    g.z = edge_diff[3 * e + 2] * inv;
    g.w = fcut;
    ssend[pos] = send;
    sgeo[pos] = g;
    unsigned int* rp = srbf + (size_t)pos * (NBF / 2);
    const float sc = fcut * inv;
#pragma unroll
    for (int kp = 0; kp < NBF / 2; ++kp) {
        const float r0 = __sinf(dist * ((2 * kp + 1) * (PI_F / 5.0f))) * sc;
        const float r1 = __sinf(dist * ((2 * kp + 2) * (PI_F / 5.0f))) * sc;
        rp[kp] = h2u(pk_rne(r0, r1));
    }
}

// ---------------------------------------------------------------------------
// Per-atom message aggregation. One block (256 thr) per atom.
// Filter dot-product via v_dot2_f32_f16 (RNE-quantized operands).
// ---------------------------------------------------------------------------
__global__ __launch_bounds__(256, 2)
void agg_kernel(const int* __restrict__ start,
                const int* __restrict__ ssend,
                const float4* __restrict__ sgeo,
                const unsigned int* __restrict__ srbf,
                const float* __restrict__ wf,    // (20,768) this layer
                const float* __restrict__ bf,    // (768)
                const unsigned short* __restrict__ so16,  // (n_atoms,768) bf16
                const unsigned short* __restrict__ nv16,  // (n_atoms,768) bf16
                const float* __restrict__ nv_old,// (n_atoms,3,256) fp32
                float* __restrict__ ns,          // += msg_s
                float* __restrict__ nv_new,      // = nv_old + sum(msg_v)
                unsigned short* __restrict__ nv16n, // bf16 copy of nv_new
                int n_atoms)
{
    __shared__ unsigned int s_rbf[ECHUNK * (NBF / 2)];  // 2560 B
    __shared__ float4 s_geo[ECHUNK];                    // 1024 B
    __shared__ int    s_send[ECHUNK];                   //  256 B

    const int f = threadIdx.x;
    const int a = blockIdx.x;

    // filter weights as packed f16 pairs (RNE): 10 dwords per component
    half2_t w0[NBF / 2], w1[NBF / 2], w2[NBF / 2];
#pragma unroll
    for (int kp = 0; kp < NBF / 2; ++kp) {
        w0[kp] = pk_rne(wf[(2 * kp) * 768 + f],       wf[(2 * kp + 1) * 768 + f]);
        w1[kp] = pk_rne(wf[(2 * kp) * 768 + 256 + f], wf[(2 * kp + 1) * 768 + 256 + f]);
        w2[kp] = pk_rne(wf[(2 * kp) * 768 + 512 + f], wf[(2 * kp + 1) * 768 + 512 + f]);
    }
    const float b0 = bf[f], b1 = bf[256 + f], b2 = bf[512 + f];

    float accs = 0.0f, av0 = 0.0f, av1 = 0.0f, av2 = 0.0f;
    const int i0 = start[a], i1 = start[a + 1];

    for (int c0 = i0; c0 < i1; c0 += ECHUNK) {
        const int cnt = min(ECHUNK, i1 - c0);
        __syncthreads();
        {
            const unsigned int* src = srbf + (size_t)c0 * (NBF / 2);
            for (int t = f; t < cnt * (NBF / 2); t += 256)
                s_rbf[t] = src[t];
            for (int t = f; t < cnt; t += 256) {
                s_geo[t] = sgeo[c0 + t];
                s_send[t] = ssend[c0 + t];
            }
        }
        __syncthreads();

        for (int e = 0; e < cnt; ++e) {
            const int send = s_send[e];
            const float4 g = s_geo[e];
            const unsigned int* rp = &s_rbf[e * (NBF / 2)];
            float f0 = g.w * b0, f1 = g.w * b1, f2 = g.w * b2;
#pragma unroll
            for (int kp = 0; kp < NBF / 2; ++kp) {
                const half2_t r = u2h(rp[kp]);
                f0 = __builtin_amdgcn_fdot2(r, w0[kp], f0, false);
                f1 = __builtin_amdgcn_fdot2(r, w1[kp], f1, false);
                f2 = __builtin_amdgcn_fdot2(r, w2[kp], f2, false);
            }

            const unsigned short* sp = so16 + (size_t)send * 768;
            const float gv = f0 * bf2f(sp[f]);
            const float ge = f1 * bf2f(sp[256 + f]);
            const float ms = f2 * bf2f(sp[512 + f]);
            accs += ms;

            const unsigned short* nvp = nv16 + (size_t)send * 768;
            av0 += fmaf(bf2f(nvp[f]),       gv, g.x * ge);
            av1 += fmaf(bf2f(nvp[256 + f]), gv, g.y * ge);
            av2 += fmaf(bf2f(nvp[512 + f]), gv, g.z * ge);
        }
    }

    ns[(size_t)a * 256 + f] += accs;
    const size_t b = (size_t)a * 768 + f;
    float nvv;
    nvv = nv_old[b]       + av0; nv_new[b]       = nvv; nv16n[b]       = f2bf(nvv);
    nvv = nv_old[b + 256] + av1; nv_new[b + 256] = nvv; nv16n[b + 256] = f2bf(nvv);
    nvv = nv_old[b + 512] + av2; nv_new[b + 512] = nvv; nv16n[b + 512] = f2bf(nvv);
}

// ---------------------------------------------------------------------------
// cat[a][0:256] = |Vv[a,:,f]| ; cat[a][256:512] = ns[a][f]
// UV layout: row (a*3+d) of 512; Uv = [0:256], Vv = [256:512]
// ---------------------------------------------------------------------------
__global__ void vncat_kernel(const float* __restrict__ UV,
                             const float* __restrict__ ns,
                             float* __restrict__ cat, int n_atoms)
{
    int i = blockIdx.x * 256 + threadIdx.x;
    if (i >= n_atoms * FDIM) return;
    int a = i >> 8, f = i & 255;
    const float v0 = UV[((size_t)a * 3 + 0) * 512 + 256 + f];
    const float v1 = UV[((size_t)a * 3 + 1) * 512 + 256 + f];
    const float v2 = UV[((size_t)a * 3 + 2) * 512 + 256 + f];
    cat[(size_t)a * 512 + f] = sqrtf(v0 * v0 + v1 * v1 + v2 * v2);
    cat[(size_t)a * 512 + 256 + f] = ns[(size_t)a * 256 + f];
}

// ---------------------------------------------------------------------------
__global__ void apply_update_kernel(const float* __restrict__ mlp,
                                    const float* __restrict__ UV,
                                    float* __restrict__ nv,
                                    float* __restrict__ ns,
                                    unsigned short* __restrict__ nv16,
                                    int n_atoms)
{
    int i = blockIdx.x * 256 + threadIdx.x;
    if (i >= n_atoms * FDIM) return;
    int a = i >> 8, f = i & 255;
    const float avv = mlp[(size_t)a * 768 + f];
    const float asv = mlp[(size_t)a * 768 + 256 + f];
    const float ass = mlp[(size_t)a * 768 + 512 + f];
    float dot = 0.0f;
#pragma unroll
    for (int d = 0; d < 3; ++d) {
        const size_t iuv = ((size_t)a * 3 + d) * 512 + f;
        const float u = UV[iuv];
        const float v = UV[iuv + 256];
        const size_t inv_ = (size_t)a * 768 + d * 256 + f;
        const float nn = fmaf(avv, u, nv[inv_]);
        nv[inv_] = nn;
        nv16[inv_] = f2bf(nn);
        dot = fmaf(u, v, dot);
    }
    const float nsv = ns[i] + fmaf(asv, dot, ass);
    ns[i] = nsv;
}

// ---------------------------------------------------------------------------
__global__ void readout_kernel(const float* __restrict__ hid,
                               const float* __restrict__ w2,
                               const float* __restrict__ b2,
                               float* __restrict__ out, int n_atoms)
{
    const int a = blockIdx.x;
    const int lane = threadIdx.x; // 64
    const float* h = hid + (size_t)a * FDIM;
    float s = 0.0f;
#pragma unroll
    for (int i = 0; i < 4; ++i)
        s += h[lane + 64 * i] * w2[lane + 64 * i];
#pragma unroll
    for (int off = 32; off > 0; off >>= 1)
        s += __shfl_down(s, off);
    if (lane == 0) out[a] = s + b2[0];
}

// ---------------------------------------------------------------------------
static inline void launch_mgemm(int act, int obf, const float* A,
                                const unsigned short* Bh, const unsigned short* Bl,
                                const float* bias, void* C,
                                int M, int N, int K, hipStream_t s)
{
    dim3 grid(N / 128, (M + 63) / 64);
    if (act) {
        if (obf) mgemm_kernel<1, 1><<<grid, 256, 0, s>>>(A, Bh, Bl, bias, C, M, N, K);
        else     mgemm_kernel<1, 0><<<grid, 256, 0, s>>>(A, Bh, Bl, bias, C, M, N, K);
    } else {
        if (obf) mgemm_kernel<0, 1><<<grid, 256, 0, s>>>(A, Bh, Bl, bias, C, M, N, K);
        else     mgemm_kernel<0, 0><<<grid, 256, 0, s>>>(A, Bh, Bl, bias, C, M, N, K);
    }
}

extern "C" void kernel_launch(void* const* d_in, const int* in_sizes, int n_in,
                              void* d_out, int out_size, void* d_ws, size_t ws_size,
                              hipStream_t stream)
{
    const int*   Z            = (const int*)  d_in[0];
    const int*   edge         = (const int*)  d_in[1];
    const float* edge_diff    = (const float*)d_in[2];
    const float* edge_dist    = (const float*)d_in[3];
    const float* embed        = (const float*)d_in[4];
    const float* msg_w_filter = (const float*)d_in[5];
    const float* msg_b_filter = (const float*)d_in[6];
    const float* msg_b1       = (const float*)d_in[8];
    const float* msg_b2       = (const float*)d_in[10];
    const float* upd_bU       = (const float*)d_in[12];
    const float* upd_bV       = (const float*)d_in[14];
    const float* upd_b1       = (const float*)d_in[16];
    const float* upd_b2       = (const float*)d_in[18];
    const float* ro_b1        = (const float*)d_in[20];
    const float* ro_w2        = (const float*)d_in[21];
    const float* ro_b2        = (const float*)d_in[22];
    float* out = (float*)d_out;

    const int n_atoms = in_sizes[0];
    const int n_edges = in_sizes[1] / 2;

    // ---- workspace layout ----
    float* p   = (float*)d_ws;
    float* ns   = p; p += (size_t)n_atoms * 256;
    float* nvA  = p; p += (size_t)n_atoms * 768;
    float* nvB  = p; p += (size_t)n_atoms * 768;
    float* s768 = p; p += (size_t)n_atoms * 768;   // cat (as Mx512) then mlp (Mx768)
    float* UV   = p; p += (size_t)n_atoms * 1536;  // fused U|V, rows = 3*n_atoms
    float* hid  = p; p += (size_t)n_atoms * 256;
    unsigned short* so16  = (unsigned short*)p;  p = (float*)(so16  + (size_t)n_atoms * 768);
    unsigned short* nv16A = (unsigned short*)p;  p = (float*)(nv16A + (size_t)n_atoms * 768);
    unsigned short* nv16B = (unsigned short*)p;  p = (float*)(nv16B + (size_t)n_atoms * 768);
    unsigned short* wTh   = (unsigned short*)p;  p = (float*)(wTh + 2228224);
    unsigned short* wTl   = (unsigned short*)p;  p = (float*)(wTl + 2228224);
    float* biasUV = p; p += 1536;
    int*   counts = (int*)p;   p += n_atoms;
    int*   cursor = (int*)p;   p += n_atoms;
    int*   startp = (int*)p;   p += n_atoms + 4;
    int*   ssend  = (int*)p;   p += n_edges;
    unsigned int* srbf = (unsigned int*)((((uintptr_t)p) + 15) & ~(uintptr_t)15);
    p = (float*)(srbf + (size_t)n_edges * (NBF / 2));
    float4* sgeo = (float4*)((((uintptr_t)p) + 15) & ~(uintptr_t)15);

    // weight-T offsets (ushort indices)
    const size_t O_MSG1 = 0, O_MSG2 = 196608, O_UV = 786432,
                 O_U1 = 1179648, O_U2 = 1572864, O_RO = 2162688;

    // ---- edge sort by recv + RBF precompute (layer-invariant) ----
    hipMemsetAsync(counts, 0, n_atoms * sizeof(int), stream);
    hist_kernel<<<(n_edges + 255) / 256, 256, 0, stream>>>(edge, counts, n_edges);
    scan_kernel<<<1, 256, 0, stream>>>(counts, startp, cursor, n_atoms);
    scatter_kernel<<<(n_edges + 255) / 256, 256, 0, stream>>>(
        edge, edge_diff, edge_dist, cursor, ssend, sgeo, srbf, n_edges);

    // ---- weights -> hi/lo bf16 transposed ----
    {
        dim3 wgrid(24, 16, 19);
        wconv_kernel<<<wgrid, 256, 0, stream>>>(
            (const float*)d_in[7], (const float*)d_in[9],
            (const float*)d_in[11], (const float*)d_in[13],
            (const float*)d_in[15], (const float*)d_in[17],
            (const float*)d_in[19], wTh, wTl);
        biascat_kernel<<<6, 256, 0, stream>>>(upd_bU, upd_bV, biasUV);
    }

    hipMemsetAsync(nvA, 0, (size_t)n_atoms * 768 * sizeof(float), stream);
    hipMemsetAsync(nv16A, 0, (size_t)n_atoms * 768 * sizeof(unsigned short), stream);
    init_ns_kernel<<<(n_atoms * 256 + 255) / 256, 256, 0, stream>>>(Z, embed, ns, n_atoms);

    float* nv_old = nvA;
    float* nv_new = nvB;
    unsigned short* nv16_old = nv16A;
    unsigned short* nv16_new = nv16B;

    for (int l = 0; l < 3; ++l) {
        // hid = silu(ns @ msg_w1 + b1)  [f32]
        launch_mgemm(1, 0, ns, wTh + O_MSG1 + (size_t)l * 65536,
                     wTl + O_MSG1 + (size_t)l * 65536, msg_b1 + l * 256,
                     hid, n_atoms, 256, 256, stream);
        // so16 = hid @ msg_w2 + b2  [bf16]
        launch_mgemm(0, 1, hid, wTh + O_MSG2 + (size_t)l * 196608,
                     wTl + O_MSG2 + (size_t)l * 196608, msg_b2 + l * 768,
                     so16, n_atoms, 768, 256, stream);

        agg_kernel<<<n_atoms, 256, 0, stream>>>(
            startp, ssend, sgeo, srbf,
            msg_w_filter + (size_t)l * NBF * 768, msg_b_filter + l * 768,
            so16, nv16_old, nv_old, ns, nv_new, nv16_new, n_atoms);

        // UV = nv_new(3M x 256) @ [wU|wV] + [bU|bV]  [f32]
        launch_mgemm(0, 0, nv_new, wTh + O_UV + (size_t)l * 131072,
                     wTl + O_UV + (size_t)l * 131072, biasUV + l * 512,
                     UV, n_atoms * 3, 512, 256, stream);

        vncat_kernel<<<(n_atoms * 256 + 255) / 256, 256, 0, stream>>>(UV, ns, s768, n_atoms);

        // hid = silu(cat @ upd_w1 + b1)  [f32], K=512
        launch_mgemm(1, 0, s768, wTh + O_U1 + (size_t)l * 131072,
                     wTl + O_U1 + (size_t)l * 131072, upd_b1 + l * 256,
                     hid, n_atoms, 256, 512, stream);
        // mlp = hid @ upd_w2 + b2  [f32] (overwrites s768)
        launch_mgemm(0, 0, hid, wTh + O_U2 + (size_t)l * 196608,
                     wTl + O_U2 + (size_t)l * 196608, upd_b2 + l * 768,
                     s768, n_atoms, 768, 256, stream);

        apply_update_kernel<<<(n_atoms * 256 + 255) / 256, 256, 0, stream>>>(
            s768, UV, nv_new, ns, nv16_new, n_atoms);

        { float* t = nv_old; nv_old = nv_new; nv_new = t; }
        { unsigned short* t = nv16_old; nv16_old = nv16_new; nv16_new = t; }
    }

    // readout
    launch_mgemm(1, 0, ns, wTh + O_RO, wTl + O_RO, ro_b1, hid, n_atoms, 256, 256, stream);
    readout_kernel<<<n_atoms, 64, 0, stream>>>(hid, ro_w2, ro_b2, out, n_atoms);
}

// Round 13
// 879.679 us; speedup vs baseline: 3.6227x; 1.0562x over previous
//
#include <hip/hip_runtime.h>
#include <math.h>

#define FDIM 256
#define NBF 20
#define PI_F 3.14159265358979323846f
#define ECHUNK 64

typedef __attribute__((ext_vector_type(8))) short short8;
typedef __attribute__((ext_vector_type(4))) float f32x4;
typedef __fp16 half2_t __attribute__((ext_vector_type(2)));

__device__ __forceinline__ float silu_f(float x) {
    return x / (1.0f + __expf(-x));
}
__device__ __forceinline__ unsigned short f2bf(float f) {
    unsigned int x = __float_as_uint(f);
    unsigned int r = (x + 0x7fffu + ((x >> 16) & 1u)) >> 16;
    return (unsigned short)r;
}
__device__ __forceinline__ float bf2f(unsigned short u) {
    return __uint_as_float(((unsigned int)u) << 16);
}
__device__ __forceinline__ unsigned int h2u(half2_t h) {
    return __builtin_bit_cast(unsigned int, h);
}
__device__ __forceinline__ half2_t u2h(unsigned int u) {
    return __builtin_bit_cast(half2_t, u);
}
// round-to-nearest-even f16 pack (NOT cvt_pkrtz, which is RTZ and biased)
__device__ __forceinline__ half2_t pk_rne(float a, float b) {
    half2_t h;
    h[0] = (__fp16)a;   // v_cvt_f16_f32 (RNE)
    h[1] = (__fp16)b;
    return h;
}

// ---------------------------------------------------------------------------
// Split-bf16 MFMA GEMM (~fp32 accuracy): C = act(A_f32 @ B + bias)
// B pre-split transposed: Bh,Bl are (N,K) bf16; B ~= Bh + Bl.
// acc = Ah*Bh + Ah*Bl + Al*Bh
// BM=64, BN=128, BK=32, 256 thr (4 waves 2x2; wave tile 32x64 = 2x4 frags).
// ---------------------------------------------------------------------------
template<int ACT, int OUTBF>
__global__ __launch_bounds__(256)
void mgemm_kernel(const float* __restrict__ A,
                  const unsigned short* __restrict__ Bh,
                  const unsigned short* __restrict__ Bl,
                  const float* __restrict__ bias,
                  void* __restrict__ Cout,
                  int M, int N, int K)
{
    __shared__ unsigned short As_hi[64][40];
    __shared__ unsigned short As_lo[64][40];
    __shared__ unsigned short Bs_hi[128][40];
    __shared__ unsigned short Bs_lo[128][40];

    const int bm = blockIdx.y * 64;
    const int bn = blockIdx.x * 128;
    const int tid = threadIdx.x;
    const int wid = tid >> 6;
    const int lane = tid & 63;
    const int wr = (wid >> 1) * 32;   // 0 / 32
    const int wc = (wid & 1) * 64;    // 0 / 64
    const int r16 = lane & 15;
    const int kg  = lane >> 4;

    f32x4 acc[2][4];
#pragma unroll
    for (int i = 0; i < 2; ++i)
#pragma unroll
        for (int j = 0; j < 4; ++j)
            acc[i][j] = (f32x4){0.f, 0.f, 0.f, 0.f};

    const int sra = tid >> 2;          // A stage row 0..63
    const int cba = (tid & 3) * 8;     // A stage col 0,8,16,24
    const int srb = tid >> 1;          // B stage row 0..127
    const int cbb = (tid & 1) * 16;    // B stage col 0/16

    for (int k0 = 0; k0 < K; k0 += 32) {
        __syncthreads();
        // ---- stage A (fp32 -> hi/lo bf16), one short8 per thread ----
        {
            const int gr = min(bm + sra, M - 1);
            const float* ap = &A[(size_t)gr * K + k0 + cba];
            short8 hv, lv;
#pragma unroll
            for (int q = 0; q < 2; ++q) {
                const float4 v = *(const float4*)(ap + q * 4);
                const float xs[4] = {v.x, v.y, v.z, v.w};
#pragma unroll
                for (int j = 0; j < 4; ++j) {
                    const int idx = q * 4 + j;
                    const unsigned short hh = f2bf(xs[j]);
                    hv[idx] = (short)hh;
                    lv[idx] = (short)f2bf(xs[j] - bf2f(hh));
                }
            }
            *(short8*)&As_hi[sra][cba] = hv;
            *(short8*)&As_lo[sra][cba] = lv;
        }
        // ---- stage B (pre-split bf16), two short8 per thread ----
        {
            const size_t bo = (size_t)(bn + srb) * K + k0 + cbb;
            *(short8*)&Bs_hi[srb][cbb]     = *(const short8*)&Bh[bo];
            *(short8*)&Bs_hi[srb][cbb + 8] = *(const short8*)&Bh[bo + 8];
            *(short8*)&Bs_lo[srb][cbb]     = *(const short8*)&Bl[bo];
            *(short8*)&Bs_lo[srb][cbb + 8] = *(const short8*)&Bl[bo + 8];
        }
        __syncthreads();

        short8 ah[2], al[2], bh4[4], bl4[4];
#pragma unroll
        for (int fr = 0; fr < 2; ++fr) {
            ah[fr] = *(const short8*)&As_hi[wr + fr * 16 + r16][kg * 8];
            al[fr] = *(const short8*)&As_lo[wr + fr * 16 + r16][kg * 8];
        }
#pragma unroll
        for (int fc = 0; fc < 4; ++fc) {
            bh4[fc] = *(const short8*)&Bs_hi[wc + fc * 16 + r16][kg * 8];
            bl4[fc] = *(const short8*)&Bs_lo[wc + fc * 16 + r16][kg * 8];
        }
#pragma unroll
        for (int fr = 0; fr < 2; ++fr)
#pragma unroll
            for (int fc = 0; fc < 4; ++fc) {
                acc[fr][fc] = __builtin_amdgcn_mfma_f32_16x16x32_bf16(
                    al[fr], bh4[fc], acc[fr][fc], 0, 0, 0);
                acc[fr][fc] = __builtin_amdgcn_mfma_f32_16x16x32_bf16(
                    ah[fr], bl4[fc], acc[fr][fc], 0, 0, 0);
                acc[fr][fc] = __builtin_amdgcn_mfma_f32_16x16x32_bf16(
                    ah[fr], bh4[fc], acc[fr][fc], 0, 0, 0);
            }
    }

    // epilogue: C/D layout col=lane&15, row=(lane>>4)*4+reg
#pragma unroll
    for (int fr = 0; fr < 2; ++fr) {
#pragma unroll
        for (int fc = 0; fc < 4; ++fc) {
            const int col = bn + wc + fc * 16 + r16;
            const int row0 = bm + wr + fr * 16 + kg * 4;
            const float bsc = bias[col];
            const f32x4 v = acc[fr][fc];
#pragma unroll
            for (int j = 0; j < 4; ++j) {
                const int row = row0 + j;
                if (row < M) {
                    float x = v[j] + bsc;
                    if (ACT) x = silu_f(x);
                    if (OUTBF)
                        ((unsigned short*)Cout)[(size_t)row * N + col] = f2bf(x);
                    else
                        ((float*)Cout)[(size_t)row * N + col] = x;
                }
            }
        }
    }
}

// ---------------------------------------------------------------------------
// Weight transpose + hi/lo bf16 split. blockIdx.z = weight id (0..18).
// ---------------------------------------------------------------------------
__global__ __launch_bounds__(256)
void wconv_kernel(const float* __restrict__ msg_w1, const float* __restrict__ msg_w2,
                  const float* __restrict__ upd_wU, const float* __restrict__ upd_wV,
                  const float* __restrict__ upd_w1, const float* __restrict__ upd_w2,
                  const float* __restrict__ ro_w1,
                  unsigned short* __restrict__ wTh, unsigned short* __restrict__ wTl)
{
    const int id = blockIdx.z;
    const float* src; int R, C; size_t doff;
    if (id < 18) {
        const int l = id / 6, w = id % 6;
        switch (w) {
        case 0: src = msg_w1 + (size_t)l * 65536;  R = 256; C = 256; doff = 0       + (size_t)l * 65536;  break;
        case 1: src = msg_w2 + (size_t)l * 196608; R = 256; C = 768; doff = 196608  + (size_t)l * 196608; break;
        case 2: src = upd_wU + (size_t)l * 65536;  R = 256; C = 256; doff = 786432  + (size_t)l * 131072; break;
        case 3: src = upd_wV + (size_t)l * 65536;  R = 256; C = 256; doff = 786432  + (size_t)l * 131072 + 65536; break;
        case 4: src = upd_w1 + (size_t)l * 131072; R = 512; C = 256; doff = 1179648 + (size_t)l * 131072; break;
        default: src = upd_w2 + (size_t)l * 196608; R = 256; C = 768; doff = 1572864 + (size_t)l * 196608; break;
        }
    } else { src = ro_w1; R = 256; C = 256; doff = 2162688; }

    if (blockIdx.x * 32 >= C || blockIdx.y * 32 >= R) return;

    __shared__ float t[32][33];
    const int x = threadIdx.x & 31, y4 = threadIdx.x >> 5;
    for (int yy = y4; yy < 32; yy += 8) {
        const int r = blockIdx.y * 32 + yy, c = blockIdx.x * 32 + x;
        t[yy][x] = (r < R && c < C) ? src[(size_t)r * C + c] : 0.f;
    }
    __syncthreads();
    for (int yy = y4; yy < 32; yy += 8) {
        const int c = blockIdx.x * 32 + yy, r = blockIdx.y * 32 + x;
        if (c < C && r < R) {
            const float v = t[x][yy];
            const unsigned short h = f2bf(v);
            wTh[doff + (size_t)c * R + r] = h;
            wTl[doff + (size_t)c * R + r] = f2bf(v - bf2f(h));
        }
    }
}

// biasUV[l][0:256]=upd_bU[l], [256:512]=upd_bV[l]
__global__ void biascat_kernel(const float* __restrict__ bU,
                               const float* __restrict__ bV,
                               float* __restrict__ o)
{
    int i = blockIdx.x * 256 + threadIdx.x;
    if (i >= 1536) return;
    int l = i >> 9, j = i & 511;
    o[i] = (j < 256) ? bU[l * 256 + j] : bV[l * 256 + j - 256];
}

// ---------------------------------------------------------------------------
__global__ void init_ns_kernel(const int* __restrict__ Z,
                               const float* __restrict__ embed,
                               float* __restrict__ ns, int n_atoms)
{
    int i = blockIdx.x * 256 + threadIdx.x;
    if (i >= n_atoms * FDIM) return;
    int a = i >> 8, f = i & 255;
    ns[i] = embed[Z[a] * FDIM + f];
}

// packed[j] = (so16[j] << 16) | nv16[j]   (bit-exact table merge)
__global__ void pack_kernel(const unsigned short* __restrict__ so16,
                            const unsigned short* __restrict__ nv16,
                            unsigned int* __restrict__ packed, int n)
{
    int i = (blockIdx.x * 256 + threadIdx.x) * 4;
    if (i + 3 < n) {
        const ushort4 s = *(const ushort4*)&so16[i];
        const ushort4 v = *(const ushort4*)&nv16[i];
        uint4 o;
        o.x = ((unsigned int)s.x << 16) | v.x;
        o.y = ((unsigned int)s.y << 16) | v.y;
        o.z = ((unsigned int)s.z << 16) | v.z;
        o.w = ((unsigned int)s.w << 16) | v.w;
        *(uint4*)&packed[i] = o;
    } else {
        for (; i < n; ++i)
            packed[i] = ((unsigned int)so16[i] << 16) | nv16[i];
    }
}

// ---------------------------------------------------------------------------
// Counting sort of edges by recv atom.
// ---------------------------------------------------------------------------
__global__ void hist_kernel(const int* __restrict__ edge, int* __restrict__ counts,
                            int n_edges)
{
    int e = blockIdx.x * 256 + threadIdx.x;
    if (e >= n_edges) return;
    atomicAdd(&counts[edge[2 * e]], 1);
}

__global__ __launch_bounds__(256)
void scan_kernel(const int* __restrict__ counts, int* __restrict__ start,
                 int* __restrict__ cursor, int n)
{
    __shared__ int sums[256];
    const int t = threadIdx.x;
    const int base = t * 20;
    int local[20];
    int s = 0;
#pragma unroll
    for (int i = 0; i < 20; ++i) {
        int c = (base + i < n) ? counts[base + i] : 0;
        local[i] = s;
        s += c;
    }
    sums[t] = s;
    __syncthreads();
    for (int off = 1; off < 256; off <<= 1) {
        int v = (t >= off) ? sums[t - off] : 0;
        __syncthreads();
        sums[t] += v;
        __syncthreads();
    }
    const int pre = (t > 0) ? sums[t - 1] : 0;
#pragma unroll
    for (int i = 0; i < 20; ++i) {
        if (base + i < n) {
            start[base + i] = pre + local[i];
            cursor[base + i] = pre + local[i];
        }
    }
    if (t == 255) start[n] = sums[255];
}

// Scatter into recv-sorted order; RBF precomputed as packed f16 pairs
// (10 dwords/edge, RNE-rounded) for v_dot2_f32_f16 consumption in agg.
__global__ void scatter_kernel(const int* __restrict__ edge,
                               const float* __restrict__ edge_diff,
                               const float* __restrict__ edge_dist,
                               int* __restrict__ cursor,
                               int* __restrict__ ssend,
                               float4* __restrict__ sgeo,
                               unsigned int* __restrict__ srbf,
                               int n_edges)
{
    int e = blockIdx.x * 256 + threadIdx.x;
    if (e >= n_edges) return;
    const int recv = edge[2 * e + 0];
    const int send = edge[2 * e + 1];
    const int pos = atomicAdd(&cursor[recv], 1);
    const float dist = edge_dist[e];
    const float inv = 1.0f / dist;
    const float fcut = (dist < 5.0f)
        ? 0.5f * (__cosf(dist * (PI_F / 5.0f)) + 1.0f) : 0.0f;
    float4 g;
    g.x = edge_diff[3 * e + 0] * inv;
    g.y = edge_diff[3 * e + 1] * inv;
    g.z = edge_diff[3 * e + 2] * inv;
    g.w = fcut;
    ssend[pos] = send;
    sgeo[pos] = g;
    unsigned int* rp = srbf + (size_t)pos * (NBF / 2);
    const float sc = fcut * inv;
#pragma unroll
    for (int kp = 0; kp < NBF / 2; ++kp) {
        const float r0 = __sinf(dist * ((2 * kp + 1) * (PI_F / 5.0f))) * sc;
        const float r1 = __sinf(dist * ((2 * kp + 2) * (PI_F / 5.0f))) * sc;
        rp[kp] = h2u(pk_rne(r0, r1));
    }
}

// ---------------------------------------------------------------------------
// Per-atom message aggregation. One block (256 thr) per atom.
// Gathers from the packed (so|nv) uint table: 3 loads/edge instead of 6.
// ---------------------------------------------------------------------------
__global__ __launch_bounds__(256, 2)
void agg_kernel(const int* __restrict__ start,
                const int* __restrict__ ssend,
                const float4* __restrict__ sgeo,
                const unsigned int* __restrict__ srbf,
                const float* __restrict__ wf,    // (20,768) this layer
                const float* __restrict__ bf,    // (768)
                const unsigned int* __restrict__ packed, // (n_atoms,768) so|nv
                const float* __restrict__ nv_old,// (n_atoms,3,256) fp32
                float* __restrict__ ns,          // += msg_s
                float* __restrict__ nv_new,      // = nv_old + sum(msg_v)
                unsigned short* __restrict__ nv16n, // bf16 copy of nv_new
                int n_atoms)
{
    __shared__ unsigned int s_rbf[ECHUNK * (NBF / 2)];  // 2560 B
    __shared__ float4 s_geo[ECHUNK];                    // 1024 B
    __shared__ int    s_send[ECHUNK];                   //  256 B

    const int f = threadIdx.x;
    const int a = blockIdx.x;

    // filter weights as packed f16 pairs (RNE): 10 dwords per component
    half2_t w0[NBF / 2], w1[NBF / 2], w2[NBF / 2];
#pragma unroll
    for (int kp = 0; kp < NBF / 2; ++kp) {
        w0[kp] = pk_rne(wf[(2 * kp) * 768 + f],       wf[(2 * kp + 1) * 768 + f]);
        w1[kp] = pk_rne(wf[(2 * kp) * 768 + 256 + f], wf[(2 * kp + 1) * 768 + 256 + f]);
        w2[kp] = pk_rne(wf[(2 * kp) * 768 + 512 + f], wf[(2 * kp + 1) * 768 + 512 + f]);
    }
    const float b0 = bf[f], b1 = bf[256 + f], b2 = bf[512 + f];

    float accs = 0.0f, av0 = 0.0f, av1 = 0.0f, av2 = 0.0f;
    const int i0 = start[a], i1 = start[a + 1];

    for (int c0 = i0; c0 < i1; c0 += ECHUNK) {
        const int cnt = min(ECHUNK, i1 - c0);
        __syncthreads();
        {
            const unsigned int* src = srbf + (size_t)c0 * (NBF / 2);
            for (int t = f; t < cnt * (NBF / 2); t += 256)
                s_rbf[t] = src[t];
            for (int t = f; t < cnt; t += 256) {
                s_geo[t] = sgeo[c0 + t];
                s_send[t] = ssend[c0 + t];
            }
        }
        __syncthreads();

#pragma unroll 2
        for (int e = 0; e < cnt; ++e) {
            const int send = s_send[e];
            const float4 g = s_geo[e];
            const unsigned int* rp = &s_rbf[e * (NBF / 2)];
            float f0 = g.w * b0, f1 = g.w * b1, f2 = g.w * b2;
#pragma unroll
            for (int kp = 0; kp < NBF / 2; ++kp) {
                const half2_t r = u2h(rp[kp]);
                f0 = __builtin_amdgcn_fdot2(r, w0[kp], f0, false);
                f1 = __builtin_amdgcn_fdot2(r, w1[kp], f1, false);
                f2 = __builtin_amdgcn_fdot2(r, w2[kp], f2, false);
            }

            const unsigned int* pp = packed + (size_t)send * 768;
            const unsigned int u0 = pp[f];
            const unsigned int u1 = pp[256 + f];
            const unsigned int u2 = pp[512 + f];
            // so in high half (direct as f32 bits); nv in low half (<<16)
            const float gv = f0 * __uint_as_float(u0 & 0xffff0000u);
            const float ge = f1 * __uint_as_float(u1 & 0xffff0000u);
            const float ms = f2 * __uint_as_float(u2 & 0xffff0000u);
            accs += ms;

            av0 += fmaf(__uint_as_float(u0 << 16), gv, g.x * ge);
            av1 += fmaf(__uint_as_float(u1 << 16), gv, g.y * ge);
            av2 += fmaf(__uint_as_float(u2 << 16), gv, g.z * ge);
        }
    }

    ns[(size_t)a * 256 + f] += accs;
    const size_t b = (size_t)a * 768 + f;
    float nvv;
    nvv = nv_old[b]       + av0; nv_new[b]       = nvv; nv16n[b]       = f2bf(nvv);
    nvv = nv_old[b + 256] + av1; nv_new[b + 256] = nvv; nv16n[b + 256] = f2bf(nvv);
    nvv = nv_old[b + 512] + av2; nv_new[b + 512] = nvv; nv16n[b + 512] = f2bf(nvv);
}

// ---------------------------------------------------------------------------
// cat[a][0:256] = |Vv[a,:,f]| ; cat[a][256:512] = ns[a][f]
// UV layout: row (a*3+d) of 512; Uv = [0:256], Vv = [256:512]
// ---------------------------------------------------------------------------
__global__ void vncat_kernel(const float* __restrict__ UV,
                             const float* __restrict__ ns,
                             float* __restrict__ cat, int n_atoms)
{
    int i = blockIdx.x * 256 + threadIdx.x;
    if (i >= n_atoms * FDIM) return;
    int a = i >> 8, f = i & 255;
    const float v0 = UV[((size_t)a * 3 + 0) * 512 + 256 + f];
    const float v1 = UV[((size_t)a * 3 + 1) * 512 + 256 + f];
    const float v2 = UV[((size_t)a * 3 + 2) * 512 + 256 + f];
    cat[(size_t)a * 512 + f] = sqrtf(v0 * v0 + v1 * v1 + v2 * v2);
    cat[(size_t)a * 512 + 256 + f] = ns[(size_t)a * 256 + f];
}

// ---------------------------------------------------------------------------
__global__ void apply_update_kernel(const float* __restrict__ mlp,
                                    const float* __restrict__ UV,
                                    float* __restrict__ nv,
                                    float* __restrict__ ns,
                                    unsigned short* __restrict__ nv16,
                                    int n_atoms)
{
    int i = blockIdx.x * 256 + threadIdx.x;
    if (i >= n_atoms * FDIM) return;
    int a = i >> 8, f = i & 255;
    const float avv = mlp[(size_t)a * 768 + f];
    const float asv = mlp[(size_t)a * 768 + 256 + f];
    const float ass = mlp[(size_t)a * 768 + 512 + f];
    float dot = 0.0f;
#pragma unroll
    for (int d = 0; d < 3; ++d) {
        const size_t iuv = ((size_t)a * 3 + d) * 512 + f;
        const float u = UV[iuv];
        const float v = UV[iuv + 256];
        const size_t inv_ = (size_t)a * 768 + d * 256 + f;
        const float nn = fmaf(avv, u, nv[inv_]);
        nv[inv_] = nn;
        nv16[inv_] = f2bf(nn);
        dot = fmaf(u, v, dot);
    }
    const float nsv = ns[i] + fmaf(asv, dot, ass);
    ns[i] = nsv;
}

// ---------------------------------------------------------------------------
__global__ void readout_kernel(const float* __restrict__ hid,
                               const float* __restrict__ w2,
                               const float* __restrict__ b2,
                               float* __restrict__ out, int n_atoms)
{
    const int a = blockIdx.x;
    const int lane = threadIdx.x; // 64
    const float* h = hid + (size_t)a * FDIM;
    float s = 0.0f;
#pragma unroll
    for (int i = 0; i < 4; ++i)
        s += h[lane + 64 * i] * w2[lane + 64 * i];
#pragma unroll
    for (int off = 32; off > 0; off >>= 1)
        s += __shfl_down(s, off);
    if (lane == 0) out[a] = s + b2[0];
}

// ---------------------------------------------------------------------------
static inline void launch_mgemm(int act, int obf, const float* A,
                                const unsigned short* Bh, const unsigned short* Bl,
                                const float* bias, void* C,
                                int M, int N, int K, hipStream_t s)
{
    dim3 grid(N / 128, (M + 63) / 64);
    if (act) {
        if (obf) mgemm_kernel<1, 1><<<grid, 256, 0, s>>>(A, Bh, Bl, bias, C, M, N, K);
        else     mgemm_kernel<1, 0><<<grid, 256, 0, s>>>(A, Bh, Bl, bias, C, M, N, K);
    } else {
        if (obf) mgemm_kernel<0, 1><<<grid, 256, 0, s>>>(A, Bh, Bl, bias, C, M, N, K);
        else     mgemm_kernel<0, 0><<<grid, 256, 0, s>>>(A, Bh, Bl, bias, C, M, N, K);
    }
}

extern "C" void kernel_launch(void* const* d_in, const int* in_sizes, int n_in,
                              void* d_out, int out_size, void* d_ws, size_t ws_size,
                              hipStream_t stream)
{
    const int*   Z            = (const int*)  d_in[0];
    const int*   edge         = (const int*)  d_in[1];
    const float* edge_diff    = (const float*)d_in[2];
    const float* edge_dist    = (const float*)d_in[3];
    const float* embed        = (const float*)d_in[4];
    const float* msg_w_filter = (const float*)d_in[5];
    const float* msg_b_filter = (const float*)d_in[6];
    const float* msg_b1       = (const float*)d_in[8];
    const float* msg_b2       = (const float*)d_in[10];
    const float* upd_bU       = (const float*)d_in[12];
    const float* upd_bV       = (const float*)d_in[14];
    const float* upd_b1       = (const float*)d_in[16];
    const float* upd_b2       = (const float*)d_in[18];
    const float* ro_b1        = (const float*)d_in[20];
    const float* ro_w2        = (const float*)d_in[21];
    const float* ro_b2        = (const float*)d_in[22];
    float* out = (float*)d_out;

    const int n_atoms = in_sizes[0];
    const int n_edges = in_sizes[1] / 2;

    // ---- workspace layout ----
    float* p   = (float*)d_ws;
    float* ns   = p; p += (size_t)n_atoms * 256;
    float* nvA  = p; p += (size_t)n_atoms * 768;
    float* nvB  = p; p += (size_t)n_atoms * 768;
    float* s768 = p; p += (size_t)n_atoms * 768;   // cat (as Mx512) then mlp (Mx768)
    float* UV   = p; p += (size_t)n_atoms * 1536;  // fused U|V, rows = 3*n_atoms
    float* hid  = p; p += (size_t)n_atoms * 256;
    unsigned short* so16  = (unsigned short*)p;  p = (float*)(so16  + (size_t)n_atoms * 768);
    unsigned short* nv16A = (unsigned short*)p;  p = (float*)(nv16A + (size_t)n_atoms * 768);
    unsigned short* nv16B = (unsigned short*)p;  p = (float*)(nv16B + (size_t)n_atoms * 768);
    unsigned int*   packed = (unsigned int*)p;   p = (float*)(packed + (size_t)n_atoms * 768);
    unsigned short* wTh   = (unsigned short*)p;  p = (float*)(wTh + 2228224);
    unsigned short* wTl   = (unsigned short*)p;  p = (float*)(wTl + 2228224);
    float* biasUV = p; p += 1536;
    int*   counts = (int*)p;   p += n_atoms;
    int*   cursor = (int*)p;   p += n_atoms;
    int*   startp = (int*)p;   p += n_atoms + 4;
    int*   ssend  = (int*)p;   p += n_edges;
    unsigned int* srbf = (unsigned int*)((((uintptr_t)p) + 15) & ~(uintptr_t)15);
    p = (float*)(srbf + (size_t)n_edges * (NBF / 2));
    float4* sgeo = (float4*)((((uintptr_t)p) + 15) & ~(uintptr_t)15);

    // weight-T offsets (ushort indices)
    const size_t O_MSG1 = 0, O_MSG2 = 196608, O_UV = 786432,
                 O_U1 = 1179648, O_U2 = 1572864, O_RO = 2162688;

    // ---- edge sort by recv + RBF precompute (layer-invariant) ----
    hipMemsetAsync(counts, 0, n_atoms * sizeof(int), stream);
    hist_kernel<<<(n_edges + 255) / 256, 256, 0, stream>>>(edge, counts, n_edges);
    scan_kernel<<<1, 256, 0, stream>>>(counts, startp, cursor, n_atoms);
    scatter_kernel<<<(n_edges + 255) / 256, 256, 0, stream>>>(
        edge, edge_diff, edge_dist, cursor, ssend, sgeo, srbf, n_edges);

    // ---- weights -> hi/lo bf16 transposed ----
    {
        dim3 wgrid(24, 16, 19);
        wconv_kernel<<<wgrid, 256, 0, stream>>>(
            (const float*)d_in[7], (const float*)d_in[9],
            (const float*)d_in[11], (const float*)d_in[13],
            (const float*)d_in[15], (const float*)d_in[17],
            (const float*)d_in[19], wTh, wTl);
        biascat_kernel<<<6, 256, 0, stream>>>(upd_bU, upd_bV, biasUV);
    }

    hipMemsetAsync(nvA, 0, (size_t)n_atoms * 768 * sizeof(float), stream);
    hipMemsetAsync(nv16A, 0, (size_t)n_atoms * 768 * sizeof(unsigned short), stream);
    init_ns_kernel<<<(n_atoms * 256 + 255) / 256, 256, 0, stream>>>(Z, embed, ns, n_atoms);

    float* nv_old = nvA;
    float* nv_new = nvB;
    unsigned short* nv16_old = nv16A;
    unsigned short* nv16_new = nv16B;

    const int nconv = n_atoms * 768;
    const int packblocks = (nconv / 4 + 255) / 256;

    for (int l = 0; l < 3; ++l) {
        // hid = silu(ns @ msg_w1 + b1)  [f32]
        launch_mgemm(1, 0, ns, wTh + O_MSG1 + (size_t)l * 65536,
                     wTl + O_MSG1 + (size_t)l * 65536, msg_b1 + l * 256,
                     hid, n_atoms, 256, 256, stream);
        // so16 = hid @ msg_w2 + b2  [bf16]
        launch_mgemm(0, 1, hid, wTh + O_MSG2 + (size_t)l * 196608,
                     wTl + O_MSG2 + (size_t)l * 196608, msg_b2 + l * 768,
                     so16, n_atoms, 768, 256, stream);

        // packed = (so16 << 16) | nv16_old   (bit-exact)
        pack_kernel<<<packblocks, 256, 0, stream>>>(so16, nv16_old, packed, nconv);

        agg_kernel<<<n_atoms, 256, 0, stream>>>(
            startp, ssend, sgeo, srbf,
            msg_w_filter + (size_t)l * NBF * 768, msg_b_filter + l * 768,
            packed, nv_old, ns, nv_new, nv16_new, n_atoms);

        // UV = nv_new(3M x 256) @ [wU|wV] + [bU|bV]  [f32]
        launch_mgemm(0, 0, nv_new, wTh + O_UV + (size_t)l * 131072,
                     wTl + O_UV + (size_t)l * 131072, biasUV + l * 512,
                     UV, n_atoms * 3, 512, 256, stream);

        vncat_kernel<<<(n_atoms * 256 + 255) / 256, 256, 0, stream>>>(UV, ns, s768, n_atoms);

        // hid = silu(cat @ upd_w1 + b1)  [f32], K=512
        launch_mgemm(1, 0, s768, wTh + O_U1 + (size_t)l * 131072,
                     wTl + O_U1 + (size_t)l * 131072, upd_b1 + l * 256,
                     hid, n_atoms, 256, 512, stream);
        // mlp = hid @ upd_w2 + b2  [f32] (overwrites s768)
        launch_mgemm(0, 0, hid, wTh + O_U2 + (size_t)l * 196608,
                     wTl + O_U2 + (size_t)l * 196608, upd_b2 + l * 768,
                     s768, n_atoms, 768, 256, stream);

        apply_update_kernel<<<(n_atoms * 256 + 255) / 256, 256, 0, stream>>>(
            s768, UV, nv_new, ns, nv16_new, n_atoms);

        { float* t = nv_old; nv_old = nv_new; nv_new = t; }
        { unsigned short* t = nv16_old; nv16_old = nv16_new; nv16_new = t; }
    }

    // readout
    launch_mgemm(1, 0, ns, wTh + O_RO, wTl + O_RO, ro_b1, hid, n_atoms, 256, 256, stream);
    readout_kernel<<<n_atoms, 64, 0, stream>>>(hid, ro_w2, ro_b2, out, n_atoms);
}